// Round 1
// baseline (240.319 us; speedup 1.0000x reference)
//
#include <hip/hip_runtime.h>

#define SLEN 2048
#define EDIM 1024
#define HNUM 16
#define DDIM 64

typedef unsigned short u16;
typedef unsigned int u32;
typedef __attribute__((ext_vector_type(8))) __bf16 bf16x8;
typedef __attribute__((ext_vector_type(4))) float f32x4;

__device__ __forceinline__ u16 f2bf(float f) {
  u32 u = __builtin_bit_cast(u32, f);
  u = (u + 0x7fffu + ((u >> 16) & 1u)) >> 16;
  return (u16)u;
}

__device__ __forceinline__ void gload_lds16(const void* g, void* l) {
  __builtin_amdgcn_global_load_lds(
      (const __attribute__((address_space(1))) void*)g,
      (__attribute__((address_space(3))) void*)l, 16, 0, 0);
}

// XOR swizzle for 128B-row LDS tiles: spread 16B slots across banks per 8-row stripe
__device__ __forceinline__ u32 swz(u32 b) { return b ^ (((b >> 7) & 7u) << 4); }

// ---------------- GEMM: A [M,K] bf16 row-major, Bt [N,K] bf16 row-major (B^T) ----------------
// MODE 0: out bf16 = acc + bias ; MODE 1: out bf16 = relu(acc+bias) ; MODE 2: out f32 = acc+bias+add
template<int MODE>
__global__ __launch_bounds__(256, 2) void gemm_bt(
    const u16* __restrict__ A, const u16* __restrict__ Bt,
    const float* __restrict__ bias, const float* __restrict__ add,
    void* __restrict__ outp, int M, int N, int K)
{
  __shared__ __align__(16) u16 As[128 * 64];
  __shared__ __align__(16) u16 Bs[128 * 64];
  const int t = threadIdx.x;
  const int lane = t & 63, wv = t >> 6;
  const int bm = blockIdx.y * 128, bn = blockIdx.x * 128;
  const int wm = (wv >> 1) * 64, wn = (wv & 1) * 64;
  f32x4 acc[4][4] = {};

  const char* Ab = (const char*)A;
  const char* Bb = (const char*)Bt;

  for (int k0 = 0; k0 < K; k0 += 64) {
    __syncthreads();
#pragma unroll
    for (int j = 0; j < 4; ++j) {
      u32 bp = (u32)wv * 1024u + (u32)lane * 16u + (u32)j * 4096u;
      u32 L = swz(bp);
      u32 row = L >> 7, colb = L & 127u;
      gload_lds16(Ab + ((size_t)(bm + row) * K + k0) * 2 + colb,
                  (char*)As + wv * 1024 + j * 4096);
      gload_lds16(Bb + ((size_t)(bn + row) * K + k0) * 2 + colb,
                  (char*)Bs + wv * 1024 + j * 4096);
    }
    __syncthreads();
#pragma unroll
    for (int ks = 0; ks < 2; ++ks) {
      bf16x8 af[4], bfr[4];
#pragma unroll
      for (int i = 0; i < 4; ++i) {
        u32 ra = (u32)(wm + i * 16 + (lane & 15));
        u32 La = (ra << 7) + (u32)ks * 64u + (u32)(lane >> 4) * 16u;
        af[i] = *(const bf16x8*)((const char*)As + (La ^ ((ra & 7u) << 4)));
        u32 rb = (u32)(wn + i * 16 + (lane & 15));
        u32 Lb = (rb << 7) + (u32)ks * 64u + (u32)(lane >> 4) * 16u;
        bfr[i] = *(const bf16x8*)((const char*)Bs + (Lb ^ ((rb & 7u) << 4)));
      }
#pragma unroll
      for (int mi = 0; mi < 4; ++mi)
#pragma unroll
        for (int ni = 0; ni < 4; ++ni)
          acc[mi][ni] = __builtin_amdgcn_mfma_f32_16x16x32_bf16(af[mi], bfr[ni], acc[mi][ni], 0, 0, 0);
    }
  }

  const int cr = (lane >> 4) * 4, cc = lane & 15;
#pragma unroll
  for (int ni = 0; ni < 4; ++ni) {
    const int col = bn + wn + ni * 16 + cc;
    const float bvv = bias[col];
#pragma unroll
    for (int mi = 0; mi < 4; ++mi) {
#pragma unroll
      for (int r = 0; r < 4; ++r) {
        const int row = bm + wm + mi * 16 + cr + r;
        float v = acc[mi][ni][r] + bvv;
        const size_t idx = (size_t)row * N + col;
        if constexpr (MODE == 0) ((u16*)outp)[idx] = f2bf(v);
        else if constexpr (MODE == 1) ((u16*)outp)[idx] = f2bf(v > 0.f ? v : 0.f);
        else ((float*)outp)[idx] = v + add[idx];
      }
    }
  }
}

// ---------------- flash attention: QKV [S,3072] bf16 (q|k|v, col = h*64+d), Vt [H,D,S] bf16 ----------------
__global__ __launch_bounds__(256, 2) void attn_kernel(
    const u16* __restrict__ qkv, const u16* __restrict__ vt, u16* __restrict__ zcat)
{
  __shared__ __align__(16) char lds[24576];  // K:0..8K  Vt:8K..16K  P: 16K + wave*2K
  char* Kl = lds;
  char* Vl = lds + 8192;
  const int t = threadIdx.x, lane = t & 63, wv = t >> 6;
  const int h = blockIdx.y;
  const int q0 = blockIdx.x * 64 + wv * 16;
  char* Pl = lds + 16384 + wv * 2048;

  // hoist Q fragments (A-operand): lane holds Q[q0+(l&15)][ds*32 + (l>>4)*8 + i]
  bf16x8 qf[2];
#pragma unroll
  for (int ds = 0; ds < 2; ++ds)
    qf[ds] = *(const bf16x8*)(qkv + (size_t)(q0 + (lane & 15)) * 3072 + h * 64 + ds * 32 + (lane >> 4) * 8);

  f32x4 zacc[4] = {};
  f32x4 mrow = {-1e30f, -1e30f, -1e30f, -1e30f};
  f32x4 ssum = {};

  for (int kt = 0; kt < SLEN / 64; ++kt) {
    __syncthreads();
    // stage K tile [64 kc][64 d] and Vt tile [64 d][64 kc], swizzled via pre-swizzled global src
#pragma unroll
    for (int j = 0; j < 2; ++j) {
      u32 bp = (u32)wv * 1024u + (u32)lane * 16u + (u32)j * 4096u;
      u32 L = swz(bp);
      u32 row = L >> 7, colb = L & 127u;
      gload_lds16((const char*)qkv + ((size_t)(kt * 64 + row) * 3072 + 1024 + h * 64) * 2 + colb,
                  Kl + wv * 1024 + j * 4096);
      gload_lds16((const char*)vt + ((size_t)(h * 64 + row) * SLEN + kt * 64) * 2 + colb,
                  Vl + wv * 1024 + j * 4096);
    }
    __syncthreads();

    // QK^T: C[16 q,16 kc] per kc-group
    f32x4 sfr[4] = {};
#pragma unroll
    for (int kcg = 0; kcg < 4; ++kcg) {
#pragma unroll
      for (int ds = 0; ds < 2; ++ds) {
        u32 rk = (u32)(kcg * 16 + (lane & 15));
        u32 L = (rk << 7) + (u32)ds * 64u + (u32)(lane >> 4) * 16u;
        bf16x8 bk = *(const bf16x8*)(Kl + (L ^ ((rk & 7u) << 4)));
        sfr[kcg] = __builtin_amdgcn_mfma_f32_16x16x32_bf16(qf[ds], bk, sfr[kcg], 0, 0, 0);
      }
    }

    // online softmax over this 64-col tile; row r of lane = q-row (lane>>4)*4+r
    f32x4 tmax;
#pragma unroll
    for (int r = 0; r < 4; ++r)
      tmax[r] = fmaxf(fmaxf(sfr[0][r], sfr[1][r]), fmaxf(sfr[2][r], sfr[3][r]));
#pragma unroll
    for (int m = 1; m < 16; m <<= 1)
#pragma unroll
      for (int r = 0; r < 4; ++r) tmax[r] = fmaxf(tmax[r], __shfl_xor(tmax[r], m));

    f32x4 newm, scl, psum;
#pragma unroll
    for (int r = 0; r < 4; ++r) {
      newm[r] = fmaxf(mrow[r], tmax[r]);
      scl[r] = __expf(mrow[r] - newm[r]);
      psum[r] = 0.f;
    }
#pragma unroll
    for (int kcg = 0; kcg < 4; ++kcg)
#pragma unroll
      for (int r = 0; r < 4; ++r) {
        float p = __expf(sfr[kcg][r] - newm[r]);
        sfr[kcg][r] = p;
        psum[r] += p;
      }
#pragma unroll
    for (int m = 1; m < 16; m <<= 1)
#pragma unroll
      for (int r = 0; r < 4; ++r) psum[r] += __shfl_xor(psum[r], m);
#pragma unroll
    for (int r = 0; r < 4; ++r) { ssum[r] = ssum[r] * scl[r] + psum[r]; mrow[r] = newm[r]; }
#pragma unroll
    for (int ni = 0; ni < 4; ++ni)
#pragma unroll
      for (int r = 0; r < 4; ++r) zacc[ni][r] *= scl[r];

    // write P (bf16) to per-wave LDS region, swizzled
#pragma unroll
    for (int kcg = 0; kcg < 4; ++kcg)
#pragma unroll
      for (int r = 0; r < 4; ++r) {
        u32 rp = (u32)((lane >> 4) * 4 + r);
        u32 L = (rp << 7) + (u32)(kcg * 16 + (lane & 15)) * 2u;
        *(u16*)(Pl + (L ^ ((rp & 7u) << 4))) = f2bf(sfr[kcg][r]);
      }
    __syncthreads();

    // PV: z[16 q, 64 d] += P[16,64] @ V[64,64]
#pragma unroll
    for (int ks = 0; ks < 2; ++ks) {
      u32 rp = (u32)(lane & 15);
      u32 Lp = (rp << 7) + (u32)ks * 64u + (u32)(lane >> 4) * 16u;
      bf16x8 ap = *(const bf16x8*)(Pl + (Lp ^ ((rp & 7u) << 4)));
#pragma unroll
      for (int ni = 0; ni < 4; ++ni) {
        u32 rv = (u32)(ni * 16 + (lane & 15));
        u32 Lv = (rv << 7) + (u32)ks * 64u + (u32)(lane >> 4) * 16u;
        bf16x8 bv = *(const bf16x8*)(Vl + (Lv ^ ((rv & 7u) << 4)));
        zacc[ni] = __builtin_amdgcn_mfma_f32_16x16x32_bf16(ap, bv, zacc[ni], 0, 0, 0);
      }
    }
  }

  // epilogue: z = (P@V)/sum / sqrt(D); concat col = h*64 + d
#pragma unroll
  for (int ni = 0; ni < 4; ++ni)
#pragma unroll
    for (int r = 0; r < 4; ++r) {
      float z = zacc[ni][r] * (0.125f / ssum[r]);
      int row = q0 + (lane >> 4) * 4 + r;
      int col = h * 64 + ni * 16 + (lane & 15);
      zcat[(size_t)row * EDIM + col] = f2bf(z);
    }
}

// ---------------- LayerNorm over E=1024; optional f32 and bf16 outputs (in-place safe) ----------------
__global__ __launch_bounds__(256) void ln_kernel(
    const float* __restrict__ in, const float* __restrict__ g, const float* __restrict__ b,
    float* __restrict__ outf, u16* __restrict__ outb)
{
  const int row = blockIdx.x, t = threadIdx.x;
  const float4* rp = (const float4*)(in + (size_t)row * EDIM);
  float4 x = rp[t];
  float s = x.x + x.y + x.z + x.w;
  float sq = x.x * x.x + x.y * x.y + x.z * x.z + x.w * x.w;
#pragma unroll
  for (int m = 1; m < 64; m <<= 1) { s += __shfl_xor(s, m); sq += __shfl_xor(sq, m); }
  __shared__ float red[8];
  const int wv = t >> 6, lane = t & 63;
  if (lane == 0) { red[wv] = s; red[4 + wv] = sq; }
  __syncthreads();
  s = red[0] + red[1] + red[2] + red[3];
  sq = red[4] + red[5] + red[6] + red[7];
  const float mu = s * (1.f / EDIM);
  const float rs = rsqrtf(sq * (1.f / EDIM) - mu * mu + 1e-5f);
  float4 gg = ((const float4*)g)[t];
  float4 bb = ((const float4*)b)[t];
  float4 y;
  y.x = (x.x - mu) * rs * gg.x + bb.x;
  y.y = (x.y - mu) * rs * gg.y + bb.y;
  y.z = (x.z - mu) * rs * gg.z + bb.z;
  y.w = (x.w - mu) * rs * gg.w + bb.w;
  if (outf) ((float4*)(outf + (size_t)row * EDIM))[t] = y;
  if (outb) {
    uint2 pk;
    pk.x = (u32)f2bf(y.x) | ((u32)f2bf(y.y) << 16);
    pk.y = (u32)f2bf(y.z) | ((u32)f2bf(y.w) << 16);
    ((uint2*)(outb + (size_t)row * EDIM))[t] = pk;
  }
}

// ---------------- prep kernels ----------------
__global__ void emb_kernel(const float4* __restrict__ a, const float4* __restrict__ b,
                           float4* __restrict__ ef, uint2* __restrict__ eb)
{
  const int i = blockIdx.x * 256 + threadIdx.x;
  float4 x = a[i], y = b[i];
  float4 e; e.x = x.x + y.x; e.y = x.y + y.y; e.z = x.z + y.z; e.w = x.w + y.w;
  ef[i] = e;
  uint2 pk;
  pk.x = (u32)f2bf(e.x) | ((u32)f2bf(e.y) << 16);
  pk.y = (u32)f2bf(e.z) | ((u32)f2bf(e.w) << 16);
  eb[i] = pk;
}

__global__ void cvt_kernel(const float4* __restrict__ in, uint2* __restrict__ out, int n4)
{
  const int i = blockIdx.x * 256 + threadIdx.x;
  if (i >= n4) return;
  float4 x = in[i];
  uint2 pk;
  pk.x = (u32)f2bf(x.x) | ((u32)f2bf(x.y) << 16);
  pk.y = (u32)f2bf(x.z) | ((u32)f2bf(x.w) << 16);
  out[i] = pk;
}

__global__ void bias3_kernel(const float* __restrict__ bq, const float* __restrict__ bk,
                             const float* __restrict__ bv, float* __restrict__ o)
{
  const int i = blockIdx.x * 256 + threadIdx.x;
  if (i >= 3072) return;
  o[i] = i < 1024 ? bq[i] : (i < 2048 ? bk[i - 1024] : bv[i - 2048]);
}

// Wq/Wk/Wv [H,E,D] f32 -> Wqkvt [3*H*D, E] bf16 (row = (w*16+h)*64+d)
__global__ __launch_bounds__(256) void wqkv_kernel(
    const float* __restrict__ Wq, const float* __restrict__ Wk, const float* __restrict__ Wv,
    u16* __restrict__ outw)
{
  __shared__ float tile[64][65];
  const int et = blockIdx.x, h = blockIdx.y, wsel = blockIdx.z;
  const float* W = wsel == 0 ? Wq : (wsel == 1 ? Wk : Wv);
  const float* src = W + ((size_t)h * EDIM + et * 64) * DDIM;
  const int t = threadIdx.x;
#pragma unroll
  for (int it = 0; it < 4; ++it) {
    int fi = (t + it * 256) * 4;
    float4 v = *(const float4*)(src + fi);
    int e = fi >> 6, d = fi & 63;
    tile[e][d] = v.x; tile[e][d + 1] = v.y; tile[e][d + 2] = v.z; tile[e][d + 3] = v.w;
  }
  __syncthreads();
  const int d = t >> 2, ec = (t & 3) * 16;
  u16* dst = outw + ((size_t)(wsel * HNUM + h) * 64 + d) * EDIM + et * 64 + ec;
#pragma unroll
  for (int i = 0; i < 16; i += 2) {
    u32 p = (u32)f2bf(tile[ec + i][d]) | ((u32)f2bf(tile[ec + i + 1][d]) << 16);
    *(u32*)(dst + i) = p;
  }
}

// QKV [S,3072] v-part -> Vt [H,D,S] bf16
__global__ __launch_bounds__(256) void vt_kernel(const u16* __restrict__ qkv, u16* __restrict__ vt)
{
  __shared__ __align__(16) u16 tile[64][80];
  const int st = blockIdx.x, h = blockIdx.y, t = threadIdx.x;
  const int sr = t >> 2, dc = (t & 3) * 16;
  const u16* src = qkv + (size_t)(st * 64 + sr) * 3072 + 2048 + h * 64 + dc;
  *(uint4*)&tile[sr][dc] = *(const uint4*)src;
  *(uint4*)&tile[sr][dc + 8] = *(const uint4*)(src + 8);
  __syncthreads();
  const int d = t >> 2, sc = (t & 3) * 16;
  u16* dst = vt + ((size_t)h * 64 + d) * SLEN + st * 64 + sc;
#pragma unroll
  for (int i = 0; i < 16; i += 2) {
    u32 p = (u32)tile[sc + i][d] | ((u32)tile[sc + i + 1][d] << 16);
    *(u32*)(dst + i) = p;
  }
}

extern "C" void kernel_launch(void* const* d_in, const int* in_sizes, int n_in,
                              void* d_out, int out_size, void* d_ws, size_t ws_size,
                              hipStream_t stream) {
  const float* xw  = (const float*)d_in[0];
  const float* xp  = (const float*)d_in[1];
  const float* Wq  = (const float*)d_in[2];
  const float* bq  = (const float*)d_in[3];
  const float* Wk  = (const float*)d_in[4];
  const float* bk  = (const float*)d_in[5];
  const float* Wv  = (const float*)d_in[6];
  const float* bv  = (const float*)d_in[7];
  const float* W0  = (const float*)d_in[8];
  const float* b0  = (const float*)d_in[9];
  const float* g1  = (const float*)d_in[10];
  const float* be1 = (const float*)d_in[11];
  const float* W1  = (const float*)d_in[12];
  const float* b1  = (const float*)d_in[13];
  const float* W2  = (const float*)d_in[14];
  const float* b2  = (const float*)d_in[15];
  const float* g2  = (const float*)d_in[16];
  const float* be2 = (const float*)d_in[17];
  float* out = (float*)d_out;
  char* ws = (char*)d_ws;

  const size_t MB = 1ull << 20;
  // lifetime-aliased workspace layout (needs ~64.1 MB)
  float* embf32 = (float*)(ws + 0);          // 8MB; dead after GEMM-W0 -> res2
  u16*   embf16 = (u16*)(ws + 8 * MB);       // 4MB; dead after GEMM-QKV -> zcat
  u16*   zcat   = (u16*)(ws + 8 * MB);
  u16*   Wqkvt  = (u16*)(ws + 12 * MB);      // 6MB; dead after GEMM-QKV
  u16*   h1     = (u16*)(ws + 12 * MB);      // 16MB (12..28), reuses Wqkvt+QKV
  u16*   QKV    = (u16*)(ws + 18 * MB);      // 12MB (18..30); dead after attn
  u16*   Vt     = (u16*)(ws + 30 * MB);      // 4MB; dead after attn
  float* res1   = (float*)(ws + 34 * MB);    // 8MB; LN1 runs in-place -> out1f
  float* out1f  = (float*)(ws + 34 * MB);
  u16*   out1b  = (u16*)(ws + 42 * MB);      // 4MB
  u16*   W0b    = (u16*)(ws + 46 * MB);      // 2MB
  u16*   W1b    = (u16*)(ws + 48 * MB);      // 8MB
  u16*   W2b    = (u16*)(ws + 56 * MB);      // 8MB
  float* bias3  = (float*)(ws + 64 * MB);    // 12KB
  float* res2   = (float*)(ws + 0);          // reuses embf32

  // prep
  emb_kernel<<<2048, 256, 0, stream>>>((const float4*)xw, (const float4*)xp,
                                       (float4*)embf32, (uint2*)embf16);
  cvt_kernel<<<1024, 256, 0, stream>>>((const float4*)W0, (uint2*)W0b, 1024 * 1024 / 4);
  cvt_kernel<<<4096, 256, 0, stream>>>((const float4*)W1, (uint2*)W1b, 4096 * 1024 / 4);
  cvt_kernel<<<4096, 256, 0, stream>>>((const float4*)W2, (uint2*)W2b, 1024 * 4096 / 4);
  bias3_kernel<<<12, 256, 0, stream>>>(bq, bk, bv, bias3);
  wqkv_kernel<<<dim3(16, 16, 3), 256, 0, stream>>>(Wq, Wk, Wv, Wqkvt);

  // QKV projection: [2048,1024] x [3072,1024]^T -> QKV bf16
  gemm_bt<0><<<dim3(3072 / 128, 2048 / 128), 256, 0, stream>>>(
      embf16, Wqkvt, bias3, nullptr, QKV, SLEN, 3072, 1024);

  vt_kernel<<<dim3(32, 16), 256, 0, stream>>>(QKV, Vt);

  attn_kernel<<<dim3(SLEN / 64, HNUM), 256, 0, stream>>>(QKV, Vt, zcat);

  // W0 proj + b0 + emb residual -> res1 (f32)
  gemm_bt<2><<<dim3(1024 / 128, 2048 / 128), 256, 0, stream>>>(
      zcat, W0b, b0, embf32, res1, SLEN, 1024, 1024);

  ln_kernel<<<SLEN, 256, 0, stream>>>(res1, g1, be1, out1f, out1b);

  // FFN up + relu -> h1 (bf16)
  gemm_bt<1><<<dim3(4096 / 128, 2048 / 128), 256, 0, stream>>>(
      out1b, W1b, b1, nullptr, h1, SLEN, 4096, 1024);

  // FFN down + b2 + out1 residual -> res2 (f32)
  gemm_bt<2><<<dim3(1024 / 128, 2048 / 128), 256, 0, stream>>>(
      h1, W2b, b2, out1f, res2, SLEN, 1024, 4096);

  ln_kernel<<<SLEN, 256, 0, stream>>>(res2, g2, be2, out, nullptr);
}

// Round 3
// 207.178 us; speedup vs baseline: 1.1600x; 1.1600x over previous
//
#include <hip/hip_runtime.h>

#define SLEN 2048
#define EDIM 1024
#define HNUM 16
#define DDIM 64

typedef unsigned short u16;
typedef unsigned int u32;
typedef __attribute__((ext_vector_type(8))) __bf16 bf16x8;
typedef __attribute__((ext_vector_type(2))) __bf16 bf16x2;
typedef __attribute__((ext_vector_type(4))) float f32x4;

__device__ __forceinline__ u16 f2bf(float f) {
  u32 u = __builtin_bit_cast(u32, f);
  u = (u + 0x7fffu + ((u >> 16) & 1u)) >> 16;
  return (u16)u;
}

__device__ __forceinline__ u32 packbf(float a, float b) {
  bf16x2 t; t[0] = (__bf16)a; t[1] = (__bf16)b;
  return __builtin_bit_cast(u32, t);
}

__device__ __forceinline__ void gload_lds16(const void* g, void* l) {
  __builtin_amdgcn_global_load_lds(
      (const __attribute__((address_space(1))) void*)g,
      (__attribute__((address_space(3))) void*)l, 16, 0, 0);
}

// XOR swizzle for 128B-row LDS tiles
__device__ __forceinline__ u32 swz(u32 b) { return b ^ (((b >> 7) & 7u) << 4); }

// ---------------- GEMM 128x128 tile: A [M,K] bf16, Bt [N,K] bf16 ----------------
// MODE 0: out bf16 = acc+bias ; MODE 1: out bf16 = relu(acc+bias) ; MODE 2: out f32 = acc+bias+add
template<int MODE>
__global__ __launch_bounds__(256, 2) void gemm_bt(
    const u16* __restrict__ A, const u16* __restrict__ Bt,
    const float* __restrict__ bias, const float* __restrict__ add,
    void* __restrict__ outp, int M, int N, int K)
{
  __shared__ __align__(16) u16 As[128 * 64];
  __shared__ __align__(16) u16 Bs[128 * 64];
  const int t = threadIdx.x;
  const int lane = t & 63, wv = t >> 6;
  const int bm = blockIdx.y * 128, bn = blockIdx.x * 128;
  const int wm = (wv >> 1) * 64, wn = (wv & 1) * 64;
  f32x4 acc[4][4] = {};

  const char* Ab = (const char*)A;
  const char* Bb = (const char*)Bt;

  for (int k0 = 0; k0 < K; k0 += 64) {
    __syncthreads();
#pragma unroll
    for (int j = 0; j < 4; ++j) {
      u32 bp = (u32)t * 16u + (u32)j * 4096u;
      u32 L = swz(bp);
      u32 row = L >> 7, colb = L & 127u;
      gload_lds16(Ab + ((size_t)(bm + row) * K + k0) * 2 + colb, (char*)As + bp);
      gload_lds16(Bb + ((size_t)(bn + row) * K + k0) * 2 + colb, (char*)Bs + bp);
    }
    __syncthreads();
#pragma unroll
    for (int ks = 0; ks < 2; ++ks) {
      bf16x8 af[4], bfr[4];
#pragma unroll
      for (int i = 0; i < 4; ++i) {
        u32 ra = (u32)(wm + i * 16 + (lane & 15));
        u32 La = (ra << 7) + (u32)ks * 64u + (u32)(lane >> 4) * 16u;
        af[i] = *(const bf16x8*)((const char*)As + (La ^ ((ra & 7u) << 4)));
        u32 rb = (u32)(wn + i * 16 + (lane & 15));
        u32 Lb = (rb << 7) + (u32)ks * 64u + (u32)(lane >> 4) * 16u;
        bfr[i] = *(const bf16x8*)((const char*)Bs + (Lb ^ ((rb & 7u) << 4)));
      }
#pragma unroll
      for (int mi = 0; mi < 4; ++mi)
#pragma unroll
        for (int ni = 0; ni < 4; ++ni)
          acc[mi][ni] = __builtin_amdgcn_mfma_f32_16x16x32_bf16(af[mi], bfr[ni], acc[mi][ni], 0, 0, 0);
    }
  }

  const int cr = (lane >> 4) * 4, cc = lane & 15;
#pragma unroll
  for (int ni = 0; ni < 4; ++ni) {
    const int col = bn + wn + ni * 16 + cc;
    const float bvv = bias[col];
#pragma unroll
    for (int mi = 0; mi < 4; ++mi) {
#pragma unroll
      for (int r = 0; r < 4; ++r) {
        const int row = bm + wm + mi * 16 + cr + r;
        float v = acc[mi][ni][r] + bvv;
        const size_t idx = (size_t)row * N + col;
        if constexpr (MODE == 0) ((u16*)outp)[idx] = f2bf(v);
        else if constexpr (MODE == 1) ((u16*)outp)[idx] = f2bf(v > 0.f ? v : 0.f);
        else ((float*)outp)[idx] = v + add[idx];
      }
    }
  }
}

// ---------------- GEMM 64x128 tile (better grid occupancy for small N) ----------------
template<int MODE>
__global__ __launch_bounds__(256, 2) void gemm_bt64(
    const u16* __restrict__ A, const u16* __restrict__ Bt,
    const float* __restrict__ bias, const float* __restrict__ add,
    void* __restrict__ outp, int M, int N, int K)
{
  __shared__ __align__(16) u16 As[64 * 64];    // 8KB
  __shared__ __align__(16) u16 Bs[128 * 64];   // 16KB
  const int t = threadIdx.x;
  const int lane = t & 63, wv = t >> 6;
  const int bm = blockIdx.y * 64, bn = blockIdx.x * 128;
  const int wm = (wv >> 1) * 32, wn = (wv & 1) * 64;
  f32x4 acc[2][4] = {};

  const char* Ab = (const char*)A;
  const char* Bb = (const char*)Bt;

  for (int k0 = 0; k0 < K; k0 += 64) {
    __syncthreads();
    {
      u32 bp = (u32)t * 16u;
      u32 L = swz(bp);
      u32 row = L >> 7, colb = L & 127u;
      gload_lds16(Ab + ((size_t)(bm + row) * K + k0) * 2 + colb, (char*)As + bp);
      u32 bp2 = bp + 4096u;
      u32 L2 = swz(bp2);
      u32 row2 = L2 >> 7, colb2 = L2 & 127u;
      gload_lds16(Ab + ((size_t)(bm + row2) * K + k0) * 2 + colb2, (char*)As + bp2);
    }
#pragma unroll
    for (int j = 0; j < 4; ++j) {
      u32 bp = (u32)t * 16u + (u32)j * 4096u;
      u32 L = swz(bp);
      u32 row = L >> 7, colb = L & 127u;
      gload_lds16(Bb + ((size_t)(bn + row) * K + k0) * 2 + colb, (char*)Bs + bp);
    }
    __syncthreads();
#pragma unroll
    for (int ks = 0; ks < 2; ++ks) {
      bf16x8 af[2], bfr[4];
#pragma unroll
      for (int i = 0; i < 2; ++i) {
        u32 ra = (u32)(wm + i * 16 + (lane & 15));
        u32 La = (ra << 7) + (u32)ks * 64u + (u32)(lane >> 4) * 16u;
        af[i] = *(const bf16x8*)((const char*)As + (La ^ ((ra & 7u) << 4)));
      }
#pragma unroll
      for (int i = 0; i < 4; ++i) {
        u32 rb = (u32)(wn + i * 16 + (lane & 15));
        u32 Lb = (rb << 7) + (u32)ks * 64u + (u32)(lane >> 4) * 16u;
        bfr[i] = *(const bf16x8*)((const char*)Bs + (Lb ^ ((rb & 7u) << 4)));
      }
#pragma unroll
      for (int mi = 0; mi < 2; ++mi)
#pragma unroll
        for (int ni = 0; ni < 4; ++ni)
          acc[mi][ni] = __builtin_amdgcn_mfma_f32_16x16x32_bf16(af[mi], bfr[ni], acc[mi][ni], 0, 0, 0);
    }
  }

  const int cr = (lane >> 4) * 4, cc = lane & 15;
#pragma unroll
  for (int ni = 0; ni < 4; ++ni) {
    const int col = bn + wn + ni * 16 + cc;
    const float bvv = bias[col];
#pragma unroll
    for (int mi = 0; mi < 2; ++mi) {
#pragma unroll
      for (int r = 0; r < 4; ++r) {
        const int row = bm + wm + mi * 16 + cr + r;
        float v = acc[mi][ni][r] + bvv;
        const size_t idx = (size_t)row * N + col;
        if constexpr (MODE == 0) ((u16*)outp)[idx] = f2bf(v);
        else if constexpr (MODE == 1) ((u16*)outp)[idx] = f2bf(v > 0.f ? v : 0.f);
        else ((float*)outp)[idx] = v + add[idx];
      }
    }
  }
}

// ---------------- flash attention v2: swapped QK^T, shfl-P, double-buffered K/V ----------------
// QKV [S,3072] bf16 (q|k|v, col = h*64+d), Vt [H,D,S] bf16
__global__ __launch_bounds__(256, 2) void attn_kernel(
    const u16* __restrict__ qkv, const u16* __restrict__ vt, u16* __restrict__ zcat)
{
  __shared__ __align__(16) char lds[32768];  // 2 bufs x (K 8KB + V 8KB)
  const int t = threadIdx.x, lane = t & 63;
  const int g = lane >> 4, qi = lane & 15;
  const int wv = t >> 6;
  const int h = blockIdx.y;
  const int q0 = blockIdx.x * 64 + wv * 16;

  // Q fragment (B-operand of swapped QK^T): lane holds Q[q0+qi][ds*32 + g*8 + i]
  bf16x8 qf[2];
#pragma unroll
  for (int ds = 0; ds < 2; ++ds)
    qf[ds] = *(const bf16x8*)(qkv + (size_t)(q0 + qi) * 3072 + h * 64 + ds * 32 + g * 8);

  // staging address precompute (linear LDS dest, swizzled global src)
  const char* kgp[2];
  const char* vgp[2];
  u32 ldo[2];
#pragma unroll
  for (int j = 0; j < 2; ++j) {
    u32 bp = (u32)t * 16u + (u32)j * 4096u;
    u32 L = swz(bp);
    u32 row = L >> 7, colb = L & 127u;
    kgp[j] = (const char*)qkv + ((size_t)row * 3072 + 1024 + h * 64) * 2 + colb;
    vgp[j] = (const char*)vt + ((size_t)(h * 64 + row)) * (SLEN * 2) + colb;
    ldo[j] = bp;
  }

  f32x4 zacc[4] = {};
  float m = -1e30f, l = 0.f;

  const int NT = SLEN / 64;
  // prologue: stage tile 0 into buf 0
  {
    char* base = lds;
#pragma unroll
    for (int j = 0; j < 2; ++j) {
      gload_lds16(kgp[j], base + ldo[j]);
      gload_lds16(vgp[j] + 0, base + 8192 + ldo[j]);
    }
  }
  __syncthreads();

  int cur = 0;
  for (int kt = 0; kt < NT; ++kt) {
    // prefetch next tile into other buffer (in flight across compute)
    if (kt + 1 < NT) {
      char* base = lds + (cur ^ 1) * 16384;
      size_t ko = (size_t)(kt + 1) * (64 * 3072 * 2);
      int vo = (kt + 1) * 128;
#pragma unroll
      for (int j = 0; j < 2; ++j) {
        gload_lds16(kgp[j] + ko, base + ldo[j]);
        gload_lds16(vgp[j] + vo, base + 8192 + ldo[j]);
      }
    }

    const char* Kl = lds + cur * 16384;
    const char* Vl = Kl + 8192;

    // QK^T swapped: C[kc][q]; lane holds P[kc=16*kcg+4*g+r][q=qi]
    float p[4][4];
#pragma unroll
    for (int kcg = 0; kcg < 4; ++kcg) {
      f32x4 s = {};
#pragma unroll
      for (int ds = 0; ds < 2; ++ds) {
        u32 rk = (u32)(kcg * 16 + qi);
        u32 L = (rk << 7) + (u32)ds * 64u + (u32)g * 16u;
        bf16x8 kf = *(const bf16x8*)(Kl + (L ^ ((rk & 7u) << 4)));
        s = __builtin_amdgcn_mfma_f32_16x16x32_bf16(kf, qf[ds], s, 0, 0, 0);
      }
#pragma unroll
      for (int r = 0; r < 4; ++r) p[kcg][r] = s[r];
    }

    // online softmax: lane-local over 16 values + 2-step cross-group reduce
    float tmax = p[0][0];
#pragma unroll
    for (int kcg = 0; kcg < 4; ++kcg)
#pragma unroll
      for (int r = 0; r < 4; ++r) tmax = fmaxf(tmax, p[kcg][r]);
    tmax = fmaxf(tmax, __shfl_xor(tmax, 16));
    tmax = fmaxf(tmax, __shfl_xor(tmax, 32));

    float newm = fmaxf(m, tmax);
    float scl = __expf(m - newm);
    float psum = 0.f;
    u32 pk[4][2];
#pragma unroll
    for (int kcg = 0; kcg < 4; ++kcg) {
#pragma unroll
      for (int r = 0; r < 4; ++r) {
        float e = __expf(p[kcg][r] - newm);
        p[kcg][r] = e;
        psum += e;
      }
      pk[kcg][0] = packbf(p[kcg][0], p[kcg][1]);
      pk[kcg][1] = packbf(p[kcg][2], p[kcg][3]);
    }
    psum += __shfl_xor(psum, 16);
    psum += __shfl_xor(psum, 32);
    l = l * scl + psum;
    m = newm;
#pragma unroll
    for (int ni = 0; ni < 4; ++ni)
#pragma unroll
      for (int r = 0; r < 4; ++r) zacc[ni][r] *= scl;

    // PV: z^T[d][q] += Vt-frag(A) x P^T-frag(B); B assembled via shfl.
    // Dest lane (g,qi), word wi needs P[ks*32+g*8+2wi .. +1][qi] which lives on
    // source lane qi+16*(2*(g&1)+(wi>>1)) in register pk[2ks+(g>>1)][wi&1].
    // The register index depends on the DEST's g, and both registers are needed
    // by different dests of the same source -> shuffle BOTH, select after.
#pragma unroll
    for (int ks = 0; ks < 2; ++ks) {
      u32 w[4];
#pragma unroll
      for (int wi = 0; wi < 4; ++wi) {
        const int src = qi + 16 * (2 * (g & 1) + (wi >> 1));
        u32 wa = (u32)__shfl((int)pk[2 * ks][wi & 1], src);
        u32 wb = (u32)__shfl((int)pk[2 * ks + 1][wi & 1], src);
        w[wi] = (g & 2) ? wb : wa;
      }
      uint4 wp = {w[0], w[1], w[2], w[3]};
      bf16x8 pb = __builtin_bit_cast(bf16x8, wp);
#pragma unroll
      for (int ni = 0; ni < 4; ++ni) {
        u32 rv = (u32)(ni * 16 + qi);
        u32 L = (rv << 7) + (u32)ks * 64u + (u32)g * 16u;
        bf16x8 vf = *(const bf16x8*)(Vl + (L ^ ((rv & 7u) << 4)));
        zacc[ni] = __builtin_amdgcn_mfma_f32_16x16x32_bf16(vf, pb, zacc[ni], 0, 0, 0);
      }
    }

    __syncthreads();   // drains prefetch vmcnt + guards buffer swap
    cur ^= 1;
  }

  // epilogue: z[q][d] = z^T[d][q] * (1/sqrt(D)) / l ; lane holds d = ni*16+g*4+r for q=qi
  const float inv = 0.125f / l;
#pragma unroll
  for (int ni = 0; ni < 4; ++ni) {
    u32 a = packbf(zacc[ni][0] * inv, zacc[ni][1] * inv);
    u32 b = packbf(zacc[ni][2] * inv, zacc[ni][3] * inv);
    uint2 st = {a, b};
    *(uint2*)(zcat + (size_t)(q0 + qi) * EDIM + h * 64 + ni * 16 + g * 4) = st;
  }
}

// ---------------- LayerNorm over E=1024 ----------------
__global__ __launch_bounds__(256) void ln_kernel(
    const float* __restrict__ in, const float* __restrict__ g, const float* __restrict__ b,
    float* __restrict__ outf, u16* __restrict__ outb)
{
  const int row = blockIdx.x, t = threadIdx.x;
  const float4* rp = (const float4*)(in + (size_t)row * EDIM);
  float4 x = rp[t];
  float s = x.x + x.y + x.z + x.w;
  float sq = x.x * x.x + x.y * x.y + x.z * x.z + x.w * x.w;
#pragma unroll
  for (int m = 1; m < 64; m <<= 1) { s += __shfl_xor(s, m); sq += __shfl_xor(sq, m); }
  __shared__ float red[8];
  const int wv = t >> 6, lane = t & 63;
  if (lane == 0) { red[wv] = s; red[4 + wv] = sq; }
  __syncthreads();
  s = red[0] + red[1] + red[2] + red[3];
  sq = red[4] + red[5] + red[6] + red[7];
  const float mu = s * (1.f / EDIM);
  const float rs = rsqrtf(sq * (1.f / EDIM) - mu * mu + 1e-5f);
  float4 gg = ((const float4*)g)[t];
  float4 bb = ((const float4*)b)[t];
  float4 y;
  y.x = (x.x - mu) * rs * gg.x + bb.x;
  y.y = (x.y - mu) * rs * gg.y + bb.y;
  y.z = (x.z - mu) * rs * gg.z + bb.z;
  y.w = (x.w - mu) * rs * gg.w + bb.w;
  if (outf) ((float4*)(outf + (size_t)row * EDIM))[t] = y;
  if (outb) {
    uint2 pkv;
    pkv.x = (u32)f2bf(y.x) | ((u32)f2bf(y.y) << 16);
    pkv.y = (u32)f2bf(y.z) | ((u32)f2bf(y.w) << 16);
    ((uint2*)(outb + (size_t)row * EDIM))[t] = pkv;
  }
}

// ---------------- prep kernels ----------------
__global__ void emb_kernel(const float4* __restrict__ a, const float4* __restrict__ b,
                           float4* __restrict__ ef, uint2* __restrict__ eb)
{
  const int i = blockIdx.x * 256 + threadIdx.x;
  float4 x = a[i], y = b[i];
  float4 e; e.x = x.x + y.x; e.y = x.y + y.y; e.z = x.z + y.z; e.w = x.w + y.w;
  ef[i] = e;
  uint2 pk;
  pk.x = (u32)f2bf(e.x) | ((u32)f2bf(e.y) << 16);
  pk.y = (u32)f2bf(e.z) | ((u32)f2bf(e.w) << 16);
  eb[i] = pk;
}

__global__ void cvt_kernel(const float4* __restrict__ in, uint2* __restrict__ out, int n4)
{
  const int i = blockIdx.x * 256 + threadIdx.x;
  if (i >= n4) return;
  float4 x = in[i];
  uint2 pk;
  pk.x = (u32)f2bf(x.x) | ((u32)f2bf(x.y) << 16);
  pk.y = (u32)f2bf(x.z) | ((u32)f2bf(x.w) << 16);
  out[i] = pk;
}

__global__ void bias3_kernel(const float* __restrict__ bq, const float* __restrict__ bk,
                             const float* __restrict__ bv, float* __restrict__ o)
{
  const int i = blockIdx.x * 256 + threadIdx.x;
  if (i >= 3072) return;
  o[i] = i < 1024 ? bq[i] : (i < 2048 ? bk[i - 1024] : bv[i - 2048]);
}

// Wq/Wk/Wv [H,E,D] f32 -> Wqkvt [3*H*D, E] bf16 (row = (w*16+h)*64+d)
__global__ __launch_bounds__(256) void wqkv_kernel(
    const float* __restrict__ Wq, const float* __restrict__ Wk, const float* __restrict__ Wv,
    u16* __restrict__ outw)
{
  __shared__ float tile[64][65];
  const int et = blockIdx.x, h = blockIdx.y, wsel = blockIdx.z;
  const float* W = wsel == 0 ? Wq : (wsel == 1 ? Wk : Wv);
  const float* src = W + ((size_t)h * EDIM + et * 64) * DDIM;
  const int t = threadIdx.x;
#pragma unroll
  for (int it = 0; it < 4; ++it) {
    int fi = (t + it * 256) * 4;
    float4 v = *(const float4*)(src + fi);
    int e = fi >> 6, d = fi & 63;
    tile[e][d] = v.x; tile[e][d + 1] = v.y; tile[e][d + 2] = v.z; tile[e][d + 3] = v.w;
  }
  __syncthreads();
  const int d = t >> 2, ec = (t & 3) * 16;
  u16* dst = outw + ((size_t)(wsel * HNUM + h) * 64 + d) * EDIM + et * 64 + ec;
#pragma unroll
  for (int i = 0; i < 16; i += 2) {
    u32 p = (u32)f2bf(tile[ec + i][d]) | ((u32)f2bf(tile[ec + i + 1][d]) << 16);
    *(u32*)(dst + i) = p;
  }
}

// QKV [S,3072] v-part -> Vt [H,D,S] bf16
__global__ __launch_bounds__(256) void vt_kernel(const u16* __restrict__ qkv, u16* __restrict__ vt)
{
  __shared__ __align__(16) u16 tile[64][80];
  const int st = blockIdx.x, h = blockIdx.y, t = threadIdx.x;
  const int sr = t >> 2, dc = (t & 3) * 16;
  const u16* src = qkv + (size_t)(st * 64 + sr) * 3072 + 2048 + h * 64 + dc;
  *(uint4*)&tile[sr][dc] = *(const uint4*)src;
  *(uint4*)&tile[sr][dc + 8] = *(const uint4*)(src + 8);
  __syncthreads();
  const int d = t >> 2, sc = (t & 3) * 16;
  u16* dst = vt + ((size_t)h * 64 + d) * SLEN + st * 64 + sc;
#pragma unroll
  for (int i = 0; i < 16; i += 2) {
    u32 p = (u32)tile[sc + i][d] | ((u32)tile[sc + i + 1][d] << 16);
    *(u32*)(dst + i) = p;
  }
}

extern "C" void kernel_launch(void* const* d_in, const int* in_sizes, int n_in,
                              void* d_out, int out_size, void* d_ws, size_t ws_size,
                              hipStream_t stream) {
  const float* xw  = (const float*)d_in[0];
  const float* xp  = (const float*)d_in[1];
  const float* Wq  = (const float*)d_in[2];
  const float* bq  = (const float*)d_in[3];
  const float* Wk  = (const float*)d_in[4];
  const float* bk  = (const float*)d_in[5];
  const float* Wv  = (const float*)d_in[6];
  const float* bv  = (const float*)d_in[7];
  const float* W0  = (const float*)d_in[8];
  const float* b0  = (const float*)d_in[9];
  const float* g1  = (const float*)d_in[10];
  const float* be1 = (const float*)d_in[11];
  const float* W1  = (const float*)d_in[12];
  const float* b1  = (const float*)d_in[13];
  const float* W2  = (const float*)d_in[14];
  const float* b2  = (const float*)d_in[15];
  const float* g2  = (const float*)d_in[16];
  const float* be2 = (const float*)d_in[17];
  float* out = (float*)d_out;
  char* ws = (char*)d_ws;

  const size_t MB = 1ull << 20;
  float* embf32 = (float*)(ws + 0);          // 8MB; dead after GEMM-W0 -> res2
  u16*   embf16 = (u16*)(ws + 8 * MB);       // 4MB; dead after GEMM-QKV -> zcat
  u16*   zcat   = (u16*)(ws + 8 * MB);
  u16*   Wqkvt  = (u16*)(ws + 12 * MB);      // 6MB; dead after GEMM-QKV
  u16*   h1     = (u16*)(ws + 12 * MB);      // 16MB (12..28), reuses Wqkvt+QKV
  u16*   QKV    = (u16*)(ws + 18 * MB);      // 12MB (18..30); dead after attn
  u16*   Vt     = (u16*)(ws + 30 * MB);      // 4MB; dead after attn
  float* res1   = (float*)(ws + 34 * MB);    // 8MB; LN1 in-place -> out1f
  float* out1f  = (float*)(ws + 34 * MB);
  u16*   out1b  = (u16*)(ws + 42 * MB);      // 4MB
  u16*   W0b    = (u16*)(ws + 46 * MB);      // 2MB
  u16*   W1b    = (u16*)(ws + 48 * MB);      // 8MB
  u16*   W2b    = (u16*)(ws + 56 * MB);      // 8MB
  float* bias3  = (float*)(ws + 64 * MB);    // 12KB
  float* res2   = (float*)(ws + 0);          // reuses embf32

  emb_kernel<<<2048, 256, 0, stream>>>((const float4*)xw, (const float4*)xp,
                                       (float4*)embf32, (uint2*)embf16);
  cvt_kernel<<<1024, 256, 0, stream>>>((const float4*)W0, (uint2*)W0b, 1024 * 1024 / 4);
  cvt_kernel<<<4096, 256, 0, stream>>>((const float4*)W1, (uint2*)W1b, 4096 * 1024 / 4);
  cvt_kernel<<<4096, 256, 0, stream>>>((const float4*)W2, (uint2*)W2b, 1024 * 4096 / 4);
  bias3_kernel<<<12, 256, 0, stream>>>(bq, bk, bv, bias3);
  wqkv_kernel<<<dim3(16, 16, 3), 256, 0, stream>>>(Wq, Wk, Wv, Wqkvt);

  // QKV projection: [2048,1024] x [3072,1024]^T -> QKV bf16  (64-row tiles: 768 blocks = 3/CU)
  gemm_bt64<0><<<dim3(3072 / 128, 2048 / 64), 256, 0, stream>>>(
      embf16, Wqkvt, bias3, nullptr, QKV, SLEN, 3072, 1024);

  vt_kernel<<<dim3(32, 16), 256, 0, stream>>>(QKV, Vt);

  attn_kernel<<<dim3(SLEN / 64, HNUM), 256, 0, stream>>>(QKV, Vt, zcat);

  // W0 proj + b0 + emb residual -> res1 (f32)   (256 blocks = 1/CU)
  gemm_bt64<2><<<dim3(1024 / 128, 2048 / 64), 256, 0, stream>>>(
      zcat, W0b, b0, embf32, res1, SLEN, 1024, 1024);

  ln_kernel<<<SLEN, 256, 0, stream>>>(res1, g1, be1, out1f, out1b);

  // FFN up + relu -> h1 (bf16)  (128^2 tiles: 512 blocks = 2/CU)
  gemm_bt<1><<<dim3(4096 / 128, 2048 / 128), 256, 0, stream>>>(
      out1b, W1b, b1, nullptr, h1, SLEN, 4096, 1024);

  // FFN down + b2 + out1 residual -> res2 (f32)  (256 blocks = 1/CU)
  gemm_bt64<2><<<dim3(1024 / 128, 2048 / 64), 256, 0, stream>>>(
      h1, W2b, b2, out1f, res2, SLEN, 1024, 4096);

  ln_kernel<<<SLEN, 256, 0, stream>>>(res2, g2, be2, out, nullptr);
}

// Round 4
// 190.603 us; speedup vs baseline: 1.2608x; 1.0870x over previous
//
#include <hip/hip_runtime.h>

#define SLEN 2048
#define EDIM 1024
#define HNUM 16
#define DDIM 64

typedef unsigned short u16;
typedef unsigned int u32;
typedef __attribute__((ext_vector_type(8))) __bf16 bf16x8;
typedef __attribute__((ext_vector_type(2))) __bf16 bf16x2;
typedef __attribute__((ext_vector_type(4))) float f32x4;

__device__ __forceinline__ u16 f2bf(float f) {
  u32 u = __builtin_bit_cast(u32, f);
  u = (u + 0x7fffu + ((u >> 16) & 1u)) >> 16;
  return (u16)u;
}

__device__ __forceinline__ u32 packbf(float a, float b) {
  bf16x2 t; t[0] = (__bf16)a; t[1] = (__bf16)b;
  return __builtin_bit_cast(u32, t);
}

__device__ __forceinline__ void gload_lds16(const void* g, void* l) {
  __builtin_amdgcn_global_load_lds(
      (const __attribute__((address_space(1))) void*)g,
      (__attribute__((address_space(3))) void*)l, 16, 0, 0);
}

// XOR swizzle for 128B-row LDS tiles
__device__ __forceinline__ u32 swz(u32 b) { return b ^ (((b >> 7) & 7u) << 4); }

// ---------------- GEMM 128x128 tile: A [M,K] bf16, Bt [N,K] bf16 ----------------
// MODE 0: out bf16 = acc+bias ; MODE 1: out bf16 = relu(acc+bias) ; MODE 2: out f32 = acc+bias+add
template<int MODE>
__global__ __launch_bounds__(256, 2) void gemm_bt(
    const u16* __restrict__ A, const u16* __restrict__ Bt,
    const float* __restrict__ bias, const float* __restrict__ add,
    void* __restrict__ outp, int M, int N, int K)
{
  __shared__ __align__(16) u16 As[128 * 64];
  __shared__ __align__(16) u16 Bs[128 * 64];
  const int t = threadIdx.x;
  const int lane = t & 63, wv = t >> 6;
  const int bm = blockIdx.y * 128, bn = blockIdx.x * 128;
  const int wm = (wv >> 1) * 64, wn = (wv & 1) * 64;
  f32x4 acc[4][4] = {};

  const char* Ab = (const char*)A;
  const char* Bb = (const char*)Bt;

  for (int k0 = 0; k0 < K; k0 += 64) {
    __syncthreads();
#pragma unroll
    for (int j = 0; j < 4; ++j) {
      u32 bp = (u32)t * 16u + (u32)j * 4096u;
      u32 L = swz(bp);
      u32 row = L >> 7, colb = L & 127u;
      gload_lds16(Ab + ((size_t)(bm + row) * K + k0) * 2 + colb, (char*)As + bp);
      gload_lds16(Bb + ((size_t)(bn + row) * K + k0) * 2 + colb, (char*)Bs + bp);
    }
    __syncthreads();
#pragma unroll
    for (int ks = 0; ks < 2; ++ks) {
      bf16x8 af[4], bfr[4];
#pragma unroll
      for (int i = 0; i < 4; ++i) {
        u32 ra = (u32)(wm + i * 16 + (lane & 15));
        u32 La = (ra << 7) + (u32)ks * 64u + (u32)(lane >> 4) * 16u;
        af[i] = *(const bf16x8*)((const char*)As + (La ^ ((ra & 7u) << 4)));
        u32 rb = (u32)(wn + i * 16 + (lane & 15));
        u32 Lb = (rb << 7) + (u32)ks * 64u + (u32)(lane >> 4) * 16u;
        bfr[i] = *(const bf16x8*)((const char*)Bs + (Lb ^ ((rb & 7u) << 4)));
      }
#pragma unroll
      for (int mi = 0; mi < 4; ++mi)
#pragma unroll
        for (int ni = 0; ni < 4; ++ni)
          acc[mi][ni] = __builtin_amdgcn_mfma_f32_16x16x32_bf16(af[mi], bfr[ni], acc[mi][ni], 0, 0, 0);
    }
  }

  const int cr = (lane >> 4) * 4, cc = lane & 15;
#pragma unroll
  for (int ni = 0; ni < 4; ++ni) {
    const int col = bn + wn + ni * 16 + cc;
    const float bvv = bias[col];
#pragma unroll
    for (int mi = 0; mi < 4; ++mi) {
#pragma unroll
      for (int r = 0; r < 4; ++r) {
        const int row = bm + wm + mi * 16 + cr + r;
        float v = acc[mi][ni][r] + bvv;
        const size_t idx = (size_t)row * N + col;
        if constexpr (MODE == 0) ((u16*)outp)[idx] = f2bf(v);
        else if constexpr (MODE == 1) ((u16*)outp)[idx] = f2bf(v > 0.f ? v : 0.f);
        else ((float*)outp)[idx] = v + add[idx];
      }
    }
  }
}

// ---------------- GEMM 64x128 tile, optional split-K over blockIdx.z ----------------
// MODE 0: out bf16 = acc+bias ; MODE 3: f32 partial (no bias), z=0 -> outp, z=1 -> part1
// lda = row stride of A and Bt (full K); KS = K-chunk length per z.
template<int MODE>
__global__ __launch_bounds__(256, 4) void gemm_bt64(
    const u16* __restrict__ A, const u16* __restrict__ Bt,
    const float* __restrict__ bias, float* __restrict__ part1,
    void* __restrict__ outp, int M, int N, int lda, int KS)
{
  __shared__ __align__(16) u16 As[64 * 64];    // 8KB
  __shared__ __align__(16) u16 Bs[128 * 64];   // 16KB
  const int t = threadIdx.x;
  const int lane = t & 63, wv = t >> 6;
  const int bm = blockIdx.y * 64, bn = blockIdx.x * 128;
  const int wm = (wv >> 1) * 32, wn = (wv & 1) * 64;
  const int koff = blockIdx.z * KS;
  f32x4 acc[2][4] = {};

  const char* Ab = (const char*)A;
  const char* Bb = (const char*)Bt;

  for (int k0 = koff; k0 < koff + KS; k0 += 64) {
    __syncthreads();
    {
      u32 bp = (u32)t * 16u;
      u32 L = swz(bp);
      u32 row = L >> 7, colb = L & 127u;
      gload_lds16(Ab + ((size_t)(bm + row) * lda + k0) * 2 + colb, (char*)As + bp);
      u32 bp2 = bp + 4096u;
      u32 L2 = swz(bp2);
      u32 row2 = L2 >> 7, colb2 = L2 & 127u;
      gload_lds16(Ab + ((size_t)(bm + row2) * lda + k0) * 2 + colb2, (char*)As + bp2);
    }
#pragma unroll
    for (int j = 0; j < 4; ++j) {
      u32 bp = (u32)t * 16u + (u32)j * 4096u;
      u32 L = swz(bp);
      u32 row = L >> 7, colb = L & 127u;
      gload_lds16(Bb + ((size_t)(bn + row) * lda + k0) * 2 + colb, (char*)Bs + bp);
    }
    __syncthreads();
#pragma unroll
    for (int ks = 0; ks < 2; ++ks) {
      bf16x8 af[2], bfr[4];
#pragma unroll
      for (int i = 0; i < 2; ++i) {
        u32 ra = (u32)(wm + i * 16 + (lane & 15));
        u32 La = (ra << 7) + (u32)ks * 64u + (u32)(lane >> 4) * 16u;
        af[i] = *(const bf16x8*)((const char*)As + (La ^ ((ra & 7u) << 4)));
      }
#pragma unroll
      for (int i = 0; i < 4; ++i) {
        u32 rb = (u32)(wn + i * 16 + (lane & 15));
        u32 Lb = (rb << 7) + (u32)ks * 64u + (u32)(lane >> 4) * 16u;
        bfr[i] = *(const bf16x8*)((const char*)Bs + (Lb ^ ((rb & 7u) << 4)));
      }
#pragma unroll
      for (int mi = 0; mi < 2; ++mi)
#pragma unroll
        for (int ni = 0; ni < 4; ++ni)
          acc[mi][ni] = __builtin_amdgcn_mfma_f32_16x16x32_bf16(af[mi], bfr[ni], acc[mi][ni], 0, 0, 0);
    }
  }

  float* po = (MODE == 3 && blockIdx.z) ? part1 : (float*)outp;
  const int cr = (lane >> 4) * 4, cc = lane & 15;
#pragma unroll
  for (int ni = 0; ni < 4; ++ni) {
    const int col = bn + wn + ni * 16 + cc;
    const float bvv = (MODE == 3) ? 0.f : bias[col];
#pragma unroll
    for (int mi = 0; mi < 2; ++mi) {
#pragma unroll
      for (int r = 0; r < 4; ++r) {
        const int row = bm + wm + mi * 16 + cr + r;
        float v = acc[mi][ni][r] + bvv;
        const size_t idx = (size_t)row * N + col;
        if constexpr (MODE == 0) ((u16*)outp)[idx] = f2bf(v);
        else if constexpr (MODE == 1) ((u16*)outp)[idx] = f2bf(v > 0.f ? v : 0.f);
        else po[idx] = v;
      }
    }
  }
}

// ---------------- split-K reduce: out = pA + pB + bias + add (all f32, row-major [2048,1024]) ----
__global__ __launch_bounds__(256) void red2_kernel(
    const float4* __restrict__ pA, const float4* __restrict__ pB,
    const float* __restrict__ bias, const float4* __restrict__ add,
    float4* __restrict__ out)
{
  const int i = blockIdx.x * 256 + threadIdx.x;   // float4 index; grid covers exactly
  float4 a = pA[i], b = pB[i], c = add[i];
  float4 g = ((const float4*)bias)[i & 255];      // col4 = i % (1024/4)
  float4 o;
  o.x = a.x + b.x + c.x + g.x;
  o.y = a.y + b.y + c.y + g.y;
  o.z = a.z + b.z + c.z + g.z;
  o.w = a.w + b.w + c.w + g.w;
  out[i] = o;
}

// ---------------- flash attention: swapped QK^T, shfl-P, double-buffered K/V ----------------
// QKV [S,3072] bf16 (q|k|v, col = h*64+d), Vt [H,D,S] bf16
__global__ __launch_bounds__(256, 2) void attn_kernel(
    const u16* __restrict__ qkv, const u16* __restrict__ vt, u16* __restrict__ zcat)
{
  __shared__ __align__(16) char lds[32768];  // 2 bufs x (K 8KB + V 8KB)
  const int t = threadIdx.x, lane = t & 63;
  const int g = lane >> 4, qi = lane & 15;
  const int wv = t >> 6;
  const int h = blockIdx.y;
  const int q0 = blockIdx.x * 64 + wv * 16;

  // Q fragment (B-operand of swapped QK^T): lane holds Q[q0+qi][ds*32 + g*8 + i]
  bf16x8 qf[2];
#pragma unroll
  for (int ds = 0; ds < 2; ++ds)
    qf[ds] = *(const bf16x8*)(qkv + (size_t)(q0 + qi) * 3072 + h * 64 + ds * 32 + g * 8);

  // staging address precompute (linear LDS dest, swizzled global src)
  const char* kgp[2];
  const char* vgp[2];
  u32 ldo[2];
#pragma unroll
  for (int j = 0; j < 2; ++j) {
    u32 bp = (u32)t * 16u + (u32)j * 4096u;
    u32 L = swz(bp);
    u32 row = L >> 7, colb = L & 127u;
    kgp[j] = (const char*)qkv + ((size_t)row * 3072 + 1024 + h * 64) * 2 + colb;
    vgp[j] = (const char*)vt + ((size_t)(h * 64 + row)) * (SLEN * 2) + colb;
    ldo[j] = bp;
  }

  f32x4 zacc[4] = {};
  float m = -1e30f, l = 0.f;

  const int NT = SLEN / 64;
  {
    char* base = lds;
#pragma unroll
    for (int j = 0; j < 2; ++j) {
      gload_lds16(kgp[j], base + ldo[j]);
      gload_lds16(vgp[j] + 0, base + 8192 + ldo[j]);
    }
  }
  __syncthreads();

  int cur = 0;
  for (int kt = 0; kt < NT; ++kt) {
    if (kt + 1 < NT) {
      char* base = lds + (cur ^ 1) * 16384;
      size_t ko = (size_t)(kt + 1) * (64 * 3072 * 2);
      int vo = (kt + 1) * 128;
#pragma unroll
      for (int j = 0; j < 2; ++j) {
        gload_lds16(kgp[j] + ko, base + ldo[j]);
        gload_lds16(vgp[j] + vo, base + 8192 + ldo[j]);
      }
    }

    const char* Kl = lds + cur * 16384;
    const char* Vl = Kl + 8192;

    // QK^T swapped: C[kc][q]; lane holds P[kc=16*kcg+4*g+r][q=qi]
    float p[4][4];
#pragma unroll
    for (int kcg = 0; kcg < 4; ++kcg) {
      f32x4 s = {};
#pragma unroll
      for (int ds = 0; ds < 2; ++ds) {
        u32 rk = (u32)(kcg * 16 + qi);
        u32 L = (rk << 7) + (u32)ds * 64u + (u32)g * 16u;
        bf16x8 kf = *(const bf16x8*)(Kl + (L ^ ((rk & 7u) << 4)));
        s = __builtin_amdgcn_mfma_f32_16x16x32_bf16(kf, qf[ds], s, 0, 0, 0);
      }
#pragma unroll
      for (int r = 0; r < 4; ++r) p[kcg][r] = s[r];
    }

    // online softmax
    float tmax = p[0][0];
#pragma unroll
    for (int kcg = 0; kcg < 4; ++kcg)
#pragma unroll
      for (int r = 0; r < 4; ++r) tmax = fmaxf(tmax, p[kcg][r]);
    tmax = fmaxf(tmax, __shfl_xor(tmax, 16));
    tmax = fmaxf(tmax, __shfl_xor(tmax, 32));

    float newm = fmaxf(m, tmax);
    float scl = __expf(m - newm);
    float psum = 0.f;
    u32 pk[4][2];
#pragma unroll
    for (int kcg = 0; kcg < 4; ++kcg) {
#pragma unroll
      for (int r = 0; r < 4; ++r) {
        float e = __expf(p[kcg][r] - newm);
        p[kcg][r] = e;
        psum += e;
      }
      pk[kcg][0] = packbf(p[kcg][0], p[kcg][1]);
      pk[kcg][1] = packbf(p[kcg][2], p[kcg][3]);
    }
    psum += __shfl_xor(psum, 16);
    psum += __shfl_xor(psum, 32);
    l = l * scl + psum;
    m = newm;
#pragma unroll
    for (int ni = 0; ni < 4; ++ni)
#pragma unroll
      for (int r = 0; r < 4; ++r) zacc[ni][r] *= scl;

    // PV: dest lane (g,qi), word wi needs P from src lane qi+16*(2*(g&1)+(wi>>1)),
    // register pk[2ks+(g>>1)][wi&1] by DEST's g -> shuffle both, select after.
#pragma unroll
    for (int ks = 0; ks < 2; ++ks) {
      u32 w[4];
#pragma unroll
      for (int wi = 0; wi < 4; ++wi) {
        const int src = qi + 16 * (2 * (g & 1) + (wi >> 1));
        u32 wa = (u32)__shfl((int)pk[2 * ks][wi & 1], src);
        u32 wb = (u32)__shfl((int)pk[2 * ks + 1][wi & 1], src);
        w[wi] = (g & 2) ? wb : wa;
      }
      uint4 wp = {w[0], w[1], w[2], w[3]};
      bf16x8 pb = __builtin_bit_cast(bf16x8, wp);
#pragma unroll
      for (int ni = 0; ni < 4; ++ni) {
        u32 rv = (u32)(ni * 16 + qi);
        u32 L = (rv << 7) + (u32)ks * 64u + (u32)g * 16u;
        bf16x8 vf = *(const bf16x8*)(Vl + (L ^ ((rv & 7u) << 4)));
        zacc[ni] = __builtin_amdgcn_mfma_f32_16x16x32_bf16(vf, pb, zacc[ni], 0, 0, 0);
      }
    }

    __syncthreads();
    cur ^= 1;
  }

  const float inv = 0.125f / l;
#pragma unroll
  for (int ni = 0; ni < 4; ++ni) {
    u32 a = packbf(zacc[ni][0] * inv, zacc[ni][1] * inv);
    u32 b = packbf(zacc[ni][2] * inv, zacc[ni][3] * inv);
    uint2 st = {a, b};
    *(uint2*)(zcat + (size_t)(q0 + qi) * EDIM + h * 64 + ni * 16 + g * 4) = st;
  }
}

// ---------------- LayerNorm over E=1024 ----------------
__global__ __launch_bounds__(256) void ln_kernel(
    const float* __restrict__ in, const float* __restrict__ g, const float* __restrict__ b,
    float* __restrict__ outf, u16* __restrict__ outb)
{
  const int row = blockIdx.x, t = threadIdx.x;
  const float4* rp = (const float4*)(in + (size_t)row * EDIM);
  float4 x = rp[t];
  float s = x.x + x.y + x.z + x.w;
  float sq = x.x * x.x + x.y * x.y + x.z * x.z + x.w * x.w;
#pragma unroll
  for (int m = 1; m < 64; m <<= 1) { s += __shfl_xor(s, m); sq += __shfl_xor(sq, m); }
  __shared__ float red[8];
  const int wv = t >> 6, lane = t & 63;
  if (lane == 0) { red[wv] = s; red[4 + wv] = sq; }
  __syncthreads();
  s = red[0] + red[1] + red[2] + red[3];
  sq = red[4] + red[5] + red[6] + red[7];
  const float mu = s * (1.f / EDIM);
  const float rs = rsqrtf(sq * (1.f / EDIM) - mu * mu + 1e-5f);
  float4 gg = ((const float4*)g)[t];
  float4 bb = ((const float4*)b)[t];
  float4 y;
  y.x = (x.x - mu) * rs * gg.x + bb.x;
  y.y = (x.y - mu) * rs * gg.y + bb.y;
  y.z = (x.z - mu) * rs * gg.z + bb.z;
  y.w = (x.w - mu) * rs * gg.w + bb.w;
  if (outf) ((float4*)(outf + (size_t)row * EDIM))[t] = y;
  if (outb) {
    uint2 pkv;
    pkv.x = (u32)f2bf(y.x) | ((u32)f2bf(y.y) << 16);
    pkv.y = (u32)f2bf(y.z) | ((u32)f2bf(y.w) << 16);
    ((uint2*)(outb + (size_t)row * EDIM))[t] = pkv;
  }
}

// ---------------- prep kernels ----------------
__global__ void emb_kernel(const float4* __restrict__ a, const float4* __restrict__ b,
                           float4* __restrict__ ef, uint2* __restrict__ eb)
{
  const int i = blockIdx.x * 256 + threadIdx.x;
  float4 x = a[i], y = b[i];
  float4 e; e.x = x.x + y.x; e.y = x.y + y.y; e.z = x.z + y.z; e.w = x.w + y.w;
  ef[i] = e;
  uint2 pk;
  pk.x = (u32)f2bf(e.x) | ((u32)f2bf(e.y) << 16);
  pk.y = (u32)f2bf(e.z) | ((u32)f2bf(e.w) << 16);
  eb[i] = pk;
}

__global__ void cvt_kernel(const float4* __restrict__ in, uint2* __restrict__ out, int n4)
{
  const int i = blockIdx.x * 256 + threadIdx.x;
  if (i >= n4) return;
  float4 x = in[i];
  uint2 pk;
  pk.x = (u32)f2bf(x.x) | ((u32)f2bf(x.y) << 16);
  pk.y = (u32)f2bf(x.z) | ((u32)f2bf(x.w) << 16);
  out[i] = pk;
}

__global__ void bias3_kernel(const float* __restrict__ bq, const float* __restrict__ bk,
                             const float* __restrict__ bv, float* __restrict__ o)
{
  const int i = blockIdx.x * 256 + threadIdx.x;
  if (i >= 3072) return;
  o[i] = i < 1024 ? bq[i] : (i < 2048 ? bk[i - 1024] : bv[i - 2048]);
}

// Wq/Wk/Wv [H,E,D] f32 -> Wqkvt [3*H*D, E] bf16 (row = (w*16+h)*64+d)
__global__ __launch_bounds__(256) void wqkv_kernel(
    const float* __restrict__ Wq, const float* __restrict__ Wk, const float* __restrict__ Wv,
    u16* __restrict__ outw)
{
  __shared__ float tile[64][65];
  const int et = blockIdx.x, h = blockIdx.y, wsel = blockIdx.z;
  const float* W = wsel == 0 ? Wq : (wsel == 1 ? Wk : Wv);
  const float* src = W + ((size_t)h * EDIM + et * 64) * DDIM;
  const int t = threadIdx.x;
#pragma unroll
  for (int it = 0; it < 4; ++it) {
    int fi = (t + it * 256) * 4;
    float4 v = *(const float4*)(src + fi);
    int e = fi >> 6, d = fi & 63;
    tile[e][d] = v.x; tile[e][d + 1] = v.y; tile[e][d + 2] = v.z; tile[e][d + 3] = v.w;
  }
  __syncthreads();
  const int d = t >> 2, ec = (t & 3) * 16;
  u16* dst = outw + ((size_t)(wsel * HNUM + h) * 64 + d) * EDIM + et * 64 + ec;
#pragma unroll
  for (int i = 0; i < 16; i += 2) {
    u32 p = (u32)f2bf(tile[ec + i][d]) | ((u32)f2bf(tile[ec + i + 1][d]) << 16);
    *(u32*)(dst + i) = p;
  }
}

// QKV [S,3072] v-part -> Vt [H,D,S] bf16
__global__ __launch_bounds__(256) void vt_kernel(const u16* __restrict__ qkv, u16* __restrict__ vt)
{
  __shared__ __align__(16) u16 tile[64][80];
  const int st = blockIdx.x, h = blockIdx.y, t = threadIdx.x;
  const int sr = t >> 2, dc = (t & 3) * 16;
  const u16* src = qkv + (size_t)(st * 64 + sr) * 3072 + 2048 + h * 64 + dc;
  *(uint4*)&tile[sr][dc] = *(const uint4*)src;
  *(uint4*)&tile[sr][dc + 8] = *(const uint4*)(src + 8);
  __syncthreads();
  const int d = t >> 2, sc = (t & 3) * 16;
  u16* dst = vt + ((size_t)h * 64 + d) * SLEN + st * 64 + sc;
#pragma unroll
  for (int i = 0; i < 16; i += 2) {
    u32 p = (u32)tile[sc + i][d] | ((u32)tile[sc + i + 1][d] << 16);
    *(u32*)(dst + i) = p;
  }
}

extern "C" void kernel_launch(void* const* d_in, const int* in_sizes, int n_in,
                              void* d_out, int out_size, void* d_ws, size_t ws_size,
                              hipStream_t stream) {
  const float* xw  = (const float*)d_in[0];
  const float* xp  = (const float*)d_in[1];
  const float* Wq  = (const float*)d_in[2];
  const float* bq  = (const float*)d_in[3];
  const float* Wk  = (const float*)d_in[4];
  const float* bk  = (const float*)d_in[5];
  const float* Wv  = (const float*)d_in[6];
  const float* bv  = (const float*)d_in[7];
  const float* W0  = (const float*)d_in[8];
  const float* b0  = (const float*)d_in[9];
  const float* g1  = (const float*)d_in[10];
  const float* be1 = (const float*)d_in[11];
  const float* W1  = (const float*)d_in[12];
  const float* b1  = (const float*)d_in[13];
  const float* W2  = (const float*)d_in[14];
  const float* b2  = (const float*)d_in[15];
  const float* g2  = (const float*)d_in[16];
  const float* be2 = (const float*)d_in[17];
  float* out = (float*)d_out;
  char* ws = (char*)d_ws;

  const size_t MB = 1ull << 20;
  // Lifetime-packed workspace (stages S0..S10), peak 64MB + bias3:
  float* embf32 = (float*)(ws + 0);          // S0 -> red2
  u16*   embf16 = (u16*)(ws + 8 * MB);       // S0 -> QKV gemm
  u16*   zcat   = (u16*)(ws + 8 * MB);       // attn -> W0 gemm
  float* res2   = (float*)(ws + 8 * MB);     // red4(2) -> LN2
  u16*   Wqkvt  = (u16*)(ws + 12 * MB);      // S0 -> QKV gemm
  u16*   h1     = (u16*)(ws + 12 * MB);      // W1 gemm -> W2 gemm (12..28)
  u16*   QKV    = (u16*)(ws + 18 * MB);      // QKV gemm -> attn (18..30)
  float* w0pA   = (float*)(ws + 18 * MB);    // W0 gemm -> red2 (18..26)
  float* w0pB   = (float*)(ws + 26 * MB);    // W0 gemm -> red2 (26..34)
  u16*   Vt     = (u16*)(ws + 30 * MB);      // vt -> attn (30..34)
  float* res1   = (float*)(ws + 34 * MB);    // red2 -> LN1 (in-place out1f)
  float* out1f  = (float*)(ws + 34 * MB);    // LN1 -> red4 (34..42)
  u16*   out1b  = (u16*)(ws + 42 * MB);      // LN1 -> W1 gemm (42..46)
  float* w2pB   = (float*)(ws + 42 * MB);    // W2 gemm -> red4 (42..50)
  u16*   W0b    = (u16*)(ws + 46 * MB);      // S0 -> W0 gemm
  u16*   W1b    = (u16*)(ws + 48 * MB);      // S0 -> W1 gemm
  u16*   W2b    = (u16*)(ws + 56 * MB);      // S0 -> W2 gemm
  float* w2pA   = (float*)(ws + 0);          // W2 gemm -> red4 (0..8, embf32 dead)
  float* bias3  = (float*)(ws + 64 * MB);    // 12KB

  emb_kernel<<<2048, 256, 0, stream>>>((const float4*)xw, (const float4*)xp,
                                       (float4*)embf32, (uint2*)embf16);
  cvt_kernel<<<1024, 256, 0, stream>>>((const float4*)W0, (uint2*)W0b, 1024 * 1024 / 4);
  cvt_kernel<<<4096, 256, 0, stream>>>((const float4*)W1, (uint2*)W1b, 4096 * 1024 / 4);
  cvt_kernel<<<4096, 256, 0, stream>>>((const float4*)W2, (uint2*)W2b, 1024 * 4096 / 4);
  bias3_kernel<<<12, 256, 0, stream>>>(bq, bk, bv, bias3);
  wqkv_kernel<<<dim3(16, 16, 3), 256, 0, stream>>>(Wq, Wk, Wv, Wqkvt);

  // QKV projection: [2048,1024] x [3072,1024]^T -> QKV bf16 (768 blocks = 3/CU)
  gemm_bt64<0><<<dim3(3072 / 128, 2048 / 64, 1), 256, 0, stream>>>(
      embf16, Wqkvt, bias3, nullptr, QKV, SLEN, 3072, 1024, 1024);

  vt_kernel<<<dim3(32, 16), 256, 0, stream>>>(QKV, Vt);

  attn_kernel<<<dim3(SLEN / 64, HNUM), 256, 0, stream>>>(QKV, Vt, zcat);

  // W0 proj, split-K=2 (512 blocks = 2/CU) -> partials; red2 adds b0 + emb residual
  gemm_bt64<3><<<dim3(1024 / 128, 2048 / 64, 2), 256, 0, stream>>>(
      zcat, W0b, nullptr, w0pB, w0pA, SLEN, 1024, 1024, 512);
  red2_kernel<<<2048, 256, 0, stream>>>((const float4*)w0pA, (const float4*)w0pB,
                                        b0, (const float4*)embf32, (float4*)res1);

  ln_kernel<<<SLEN, 256, 0, stream>>>(res1, g1, be1, out1f, out1b);

  // FFN up + relu -> h1 (bf16) (512 blocks = 2/CU)
  gemm_bt<1><<<dim3(4096 / 128, 2048 / 128), 256, 0, stream>>>(
      out1b, W1b, b1, nullptr, h1, SLEN, 4096, 1024);

  // FFN down, split-K=2 (512 blocks = 2/CU) -> partials; red2 adds b2 + out1 residual
  gemm_bt64<3><<<dim3(1024 / 128, 2048 / 64, 2), 256, 0, stream>>>(
      h1, W2b, nullptr, w2pB, w2pA, SLEN, 1024, 4096, 2048);
  red2_kernel<<<2048, 256, 0, stream>>>((const float4*)w2pA, (const float4*)w2pB,
                                        b2, (const float4*)out1f, (float4*)res2);

  ln_kernel<<<SLEN, 256, 0, stream>>>(res2, g2, be2, out, nullptr);
}

// Round 6
// 187.201 us; speedup vs baseline: 1.2838x; 1.0182x over previous
//
#include <hip/hip_runtime.h>

#define SLEN 2048
#define EDIM 1024
#define HNUM 16
#define DDIM 64

typedef unsigned short u16;
typedef unsigned int u32;
typedef __attribute__((ext_vector_type(8))) __bf16 bf16x8;
typedef __attribute__((ext_vector_type(2))) __bf16 bf16x2;
typedef __attribute__((ext_vector_type(4))) float f32x4;

__device__ __forceinline__ u16 f2bf(float f) {
  u32 u = __builtin_bit_cast(u32, f);
  u = (u + 0x7fffu + ((u >> 16) & 1u)) >> 16;
  return (u16)u;
}

__device__ __forceinline__ float bf2f(u16 v) {
  u32 u = ((u32)v) << 16;
  return __builtin_bit_cast(float, u);
}

__device__ __forceinline__ u32 packbf(float a, float b) {
  bf16x2 t; t[0] = (__bf16)a; t[1] = (__bf16)b;
  return __builtin_bit_cast(u32, t);
}

__device__ __forceinline__ void gload_lds16(const void* g, void* l) {
  __builtin_amdgcn_global_load_lds(
      (const __attribute__((address_space(1))) void*)g,
      (__attribute__((address_space(3))) void*)l, 16, 0, 0);
}

// XOR swizzle for 128B-row LDS tiles
__device__ __forceinline__ u32 swz(u32 b) { return b ^ (((b >> 7) & 7u) << 4); }

// ---------------- GEMM 128x128 tile: A [M,K] bf16, Bt [N,K] bf16 ----------------
// MODE 0: out bf16 = acc+bias ; MODE 1: out bf16 = relu(acc+bias) ; MODE 2: out f32 = acc+bias+add
template<int MODE>
__global__ __launch_bounds__(256, 2) void gemm_bt(
    const u16* __restrict__ A, const u16* __restrict__ Bt,
    const float* __restrict__ bias, const float* __restrict__ add,
    void* __restrict__ outp, int M, int N, int K)
{
  __shared__ __align__(16) u16 As[128 * 64];
  __shared__ __align__(16) u16 Bs[128 * 64];
  const int t = threadIdx.x;
  const int lane = t & 63, wv = t >> 6;
  const int bm = blockIdx.y * 128, bn = blockIdx.x * 128;
  const int wm = (wv >> 1) * 64, wn = (wv & 1) * 64;
  f32x4 acc[4][4] = {};

  const char* Ab = (const char*)A;
  const char* Bb = (const char*)Bt;

  for (int k0 = 0; k0 < K; k0 += 64) {
    __syncthreads();
#pragma unroll
    for (int j = 0; j < 4; ++j) {
      u32 bp = (u32)t * 16u + (u32)j * 4096u;
      u32 L = swz(bp);
      u32 row = L >> 7, colb = L & 127u;
      gload_lds16(Ab + ((size_t)(bm + row) * K + k0) * 2 + colb, (char*)As + bp);
      gload_lds16(Bb + ((size_t)(bn + row) * K + k0) * 2 + colb, (char*)Bs + bp);
    }
    __syncthreads();
#pragma unroll
    for (int ks = 0; ks < 2; ++ks) {
      bf16x8 af[4], bfr[4];
#pragma unroll
      for (int i = 0; i < 4; ++i) {
        u32 ra = (u32)(wm + i * 16 + (lane & 15));
        u32 La = (ra << 7) + (u32)ks * 64u + (u32)(lane >> 4) * 16u;
        af[i] = *(const bf16x8*)((const char*)As + (La ^ ((ra & 7u) << 4)));
        u32 rb = (u32)(wn + i * 16 + (lane & 15));
        u32 Lb = (rb << 7) + (u32)ks * 64u + (u32)(lane >> 4) * 16u;
        bfr[i] = *(const bf16x8*)((const char*)Bs + (Lb ^ ((rb & 7u) << 4)));
      }
#pragma unroll
      for (int mi = 0; mi < 4; ++mi)
#pragma unroll
        for (int ni = 0; ni < 4; ++ni)
          acc[mi][ni] = __builtin_amdgcn_mfma_f32_16x16x32_bf16(af[mi], bfr[ni], acc[mi][ni], 0, 0, 0);
    }
  }

  const int cr = (lane >> 4) * 4, cc = lane & 15;
#pragma unroll
  for (int ni = 0; ni < 4; ++ni) {
    const int col = bn + wn + ni * 16 + cc;
    const float bvv = bias[col];
#pragma unroll
    for (int mi = 0; mi < 4; ++mi) {
#pragma unroll
      for (int r = 0; r < 4; ++r) {
        const int row = bm + wm + mi * 16 + cr + r;
        float v = acc[mi][ni][r] + bvv;
        const size_t idx = (size_t)row * N + col;
        if constexpr (MODE == 0) ((u16*)outp)[idx] = f2bf(v);
        else if constexpr (MODE == 1) ((u16*)outp)[idx] = f2bf(v > 0.f ? v : 0.f);
        else ((float*)outp)[idx] = v + add[idx];
      }
    }
  }
}

// ---------------- GEMM 64x128 tile, optional split-K over blockIdx.z ----------------
// MODE 0: out bf16 = acc+bias ; MODE 3: f32 partial (no bias), z=0 -> outp, z=1 -> part1
template<int MODE>
__global__ __launch_bounds__(256, 4) void gemm_bt64(
    const u16* __restrict__ A, const u16* __restrict__ Bt,
    const float* __restrict__ bias, float* __restrict__ part1,
    void* __restrict__ outp, int M, int N, int lda, int KS)
{
  __shared__ __align__(16) u16 As[64 * 64];    // 8KB
  __shared__ __align__(16) u16 Bs[128 * 64];   // 16KB
  const int t = threadIdx.x;
  const int lane = t & 63, wv = t >> 6;
  const int bm = blockIdx.y * 64, bn = blockIdx.x * 128;
  const int wm = (wv >> 1) * 32, wn = (wv & 1) * 64;
  const int koff = blockIdx.z * KS;
  f32x4 acc[2][4] = {};

  const char* Ab = (const char*)A;
  const char* Bb = (const char*)Bt;

  for (int k0 = koff; k0 < koff + KS; k0 += 64) {
    __syncthreads();
    {
      u32 bp = (u32)t * 16u;
      u32 L = swz(bp);
      u32 row = L >> 7, colb = L & 127u;
      gload_lds16(Ab + ((size_t)(bm + row) * lda + k0) * 2 + colb, (char*)As + bp);
      u32 bp2 = bp + 4096u;
      u32 L2 = swz(bp2);
      u32 row2 = L2 >> 7, colb2 = L2 & 127u;
      gload_lds16(Ab + ((size_t)(bm + row2) * lda + k0) * 2 + colb2, (char*)As + bp2);
    }
#pragma unroll
    for (int j = 0; j < 4; ++j) {
      u32 bp = (u32)t * 16u + (u32)j * 4096u;
      u32 L = swz(bp);
      u32 row = L >> 7, colb = L & 127u;
      gload_lds16(Bb + ((size_t)(bn + row) * lda + k0) * 2 + colb, (char*)Bs + bp);
    }
    __syncthreads();
#pragma unroll
    for (int ks = 0; ks < 2; ++ks) {
      bf16x8 af[2], bfr[4];
#pragma unroll
      for (int i = 0; i < 2; ++i) {
        u32 ra = (u32)(wm + i * 16 + (lane & 15));
        u32 La = (ra << 7) + (u32)ks * 64u + (u32)(lane >> 4) * 16u;
        af[i] = *(const bf16x8*)((const char*)As + (La ^ ((ra & 7u) << 4)));
      }
#pragma unroll
      for (int i = 0; i < 4; ++i) {
        u32 rb = (u32)(wn + i * 16 + (lane & 15));
        u32 Lb = (rb << 7) + (u32)ks * 64u + (u32)(lane >> 4) * 16u;
        bfr[i] = *(const bf16x8*)((const char*)Bs + (Lb ^ ((rb & 7u) << 4)));
      }
#pragma unroll
      for (int mi = 0; mi < 2; ++mi)
#pragma unroll
        for (int ni = 0; ni < 4; ++ni)
          acc[mi][ni] = __builtin_amdgcn_mfma_f32_16x16x32_bf16(af[mi], bfr[ni], acc[mi][ni], 0, 0, 0);
    }
  }

  float* po = (MODE == 3 && blockIdx.z) ? part1 : (float*)outp;
  const int cr = (lane >> 4) * 4, cc = lane & 15;
#pragma unroll
  for (int ni = 0; ni < 4; ++ni) {
    const int col = bn + wn + ni * 16 + cc;
    const float bvv = (MODE == 3) ? 0.f : bias[col];
#pragma unroll
    for (int mi = 0; mi < 2; ++mi) {
#pragma unroll
      for (int r = 0; r < 4; ++r) {
        const int row = bm + wm + mi * 16 + cr + r;
        float v = acc[mi][ni][r] + bvv;
        const size_t idx = (size_t)row * N + col;
        if constexpr (MODE == 0) ((u16*)outp)[idx] = f2bf(v);
        else if constexpr (MODE == 1) ((u16*)outp)[idx] = f2bf(v > 0.f ? v : 0.f);
        else po[idx] = v;
      }
    }
  }
}

// ---------------- split-K reduce: out = pA + pB + bias + add ----------------
__global__ __launch_bounds__(256) void red2_kernel(
    const float4* __restrict__ pA, const float4* __restrict__ pB,
    const float* __restrict__ bias, const float4* __restrict__ add,
    float4* __restrict__ out)
{
  const int i = blockIdx.x * 256 + threadIdx.x;
  float4 a = pA[i], b = pB[i], c = add[i];
  float4 g = ((const float4*)bias)[i & 255];
  float4 o;
  o.x = a.x + b.x + c.x + g.x;
  o.y = a.y + b.y + c.y + g.y;
  o.z = a.z + b.z + c.z + g.z;
  o.w = a.w + b.w + c.w + g.w;
  out[i] = o;
}

// ---------------- flash attention, KV-split-2: swapped QK^T, shfl-P, dbuf K/V ----------------
// Block (qt, h, z): q-rows qt*64..+63, keys z*1024..+1023. Raw partials:
// zp bf16 [bid][64 q][64 d], ml float2 [bid][64 q]; bid = (h*32+qt)*2+z.
__global__ __launch_bounds__(256, 4) void attn_kernel(
    const u16* __restrict__ qkv, const u16* __restrict__ vt,
    u16* __restrict__ zp, float2* __restrict__ mlb)
{
  __shared__ __align__(16) char lds[32768];  // 2 bufs x (K 8KB + V 8KB)
  const int t = threadIdx.x, lane = t & 63;
  const int g = lane >> 4, qi = lane & 15;
  const int wv = t >> 6;
  const int h = blockIdx.y;
  const int q0 = blockIdx.x * 64 + wv * 16;
  const int kt0 = blockIdx.z * (SLEN / 128);      // 16 tiles of 64 keys per split
  const int ktE = kt0 + SLEN / 128;

  // Q fragment (B-operand of swapped QK^T): lane holds Q[q0+qi][ds*32 + g*8 + i]
  bf16x8 qf[2];
#pragma unroll
  for (int ds = 0; ds < 2; ++ds)
    qf[ds] = *(const bf16x8*)(qkv + (size_t)(q0 + qi) * 3072 + h * 64 + ds * 32 + g * 8);

  // staging address precompute (linear LDS dest, swizzled global src)
  const char* kgp[2];
  const char* vgp[2];
  u32 ldo[2];
#pragma unroll
  for (int j = 0; j < 2; ++j) {
    u32 bp = (u32)t * 16u + (u32)j * 4096u;
    u32 L = swz(bp);
    u32 row = L >> 7, colb = L & 127u;
    kgp[j] = (const char*)qkv + ((size_t)row * 3072 + 1024 + h * 64) * 2 + colb;
    vgp[j] = (const char*)vt + ((size_t)(h * 64 + row)) * (SLEN * 2) + colb;
    ldo[j] = bp;
  }

  f32x4 zacc[4] = {};
  float m = -1e30f, l = 0.f;

  // prologue: stage tile kt0 into buf 0
  {
    char* base = lds;
    size_t ko = (size_t)kt0 * (64 * 3072 * 2);
    int vo = kt0 * 128;
#pragma unroll
    for (int j = 0; j < 2; ++j) {
      gload_lds16(kgp[j] + ko, base + ldo[j]);
      gload_lds16(vgp[j] + vo, base + 8192 + ldo[j]);
    }
  }
  __syncthreads();

  int cur = 0;
  for (int kt = kt0; kt < ktE; ++kt) {
    if (kt + 1 < ktE) {
      char* base = lds + (cur ^ 1) * 16384;
      size_t ko = (size_t)(kt + 1) * (64 * 3072 * 2);
      int vo = (kt + 1) * 128;
#pragma unroll
      for (int j = 0; j < 2; ++j) {
        gload_lds16(kgp[j] + ko, base + ldo[j]);
        gload_lds16(vgp[j] + vo, base + 8192 + ldo[j]);
      }
    }

    const char* Kl = lds + cur * 16384;
    const char* Vl = Kl + 8192;

    // QK^T swapped: C[kc][q]; lane holds P[kc=16*kcg+4*g+r][q=qi]
    float p[4][4];
#pragma unroll
    for (int kcg = 0; kcg < 4; ++kcg) {
      f32x4 s = {};
#pragma unroll
      for (int ds = 0; ds < 2; ++ds) {
        u32 rk = (u32)(kcg * 16 + qi);
        u32 L = (rk << 7) + (u32)ds * 64u + (u32)g * 16u;
        bf16x8 kf = *(const bf16x8*)(Kl + (L ^ ((rk & 7u) << 4)));
        s = __builtin_amdgcn_mfma_f32_16x16x32_bf16(kf, qf[ds], s, 0, 0, 0);
      }
#pragma unroll
      for (int r = 0; r < 4; ++r) p[kcg][r] = s[r];
    }

    // online softmax
    float tmax = p[0][0];
#pragma unroll
    for (int kcg = 0; kcg < 4; ++kcg)
#pragma unroll
      for (int r = 0; r < 4; ++r) tmax = fmaxf(tmax, p[kcg][r]);
    tmax = fmaxf(tmax, __shfl_xor(tmax, 16));
    tmax = fmaxf(tmax, __shfl_xor(tmax, 32));

    float newm = fmaxf(m, tmax);
    float scl = __expf(m - newm);
    float psum = 0.f;
    u32 pk[4][2];
#pragma unroll
    for (int kcg = 0; kcg < 4; ++kcg) {
#pragma unroll
      for (int r = 0; r < 4; ++r) {
        float e = __expf(p[kcg][r] - newm);
        p[kcg][r] = e;
        psum += e;
      }
      pk[kcg][0] = packbf(p[kcg][0], p[kcg][1]);
      pk[kcg][1] = packbf(p[kcg][2], p[kcg][3]);
    }
    psum += __shfl_xor(psum, 16);
    psum += __shfl_xor(psum, 32);
    l = l * scl + psum;
    m = newm;
#pragma unroll
    for (int ni = 0; ni < 4; ++ni)
#pragma unroll
      for (int r = 0; r < 4; ++r) zacc[ni][r] *= scl;

    // PV: dest lane (g,qi), word wi <- src lane qi+16*(2*(g&1)+(wi>>1)),
    // register pk[2ks+(g>>1)][wi&1] by DEST's g -> shuffle both, select after.
#pragma unroll
    for (int ks = 0; ks < 2; ++ks) {
      u32 w[4];
#pragma unroll
      for (int wi = 0; wi < 4; ++wi) {
        const int src = qi + 16 * (2 * (g & 1) + (wi >> 1));
        u32 wa = (u32)__shfl((int)pk[2 * ks][wi & 1], src);
        u32 wb = (u32)__shfl((int)pk[2 * ks + 1][wi & 1], src);
        w[wi] = (g & 2) ? wb : wa;
      }
      uint4 wp = {w[0], w[1], w[2], w[3]};
      bf16x8 pb = __builtin_bit_cast(bf16x8, wp);
#pragma unroll
      for (int ni = 0; ni < 4; ++ni) {
        u32 rv = (u32)(ni * 16 + qi);
        u32 L = (rv << 7) + (u32)ks * 64u + (u32)g * 16u;
        bf16x8 vf = *(const bf16x8*)(Vl + (L ^ ((rv & 7u) << 4)));
        zacc[ni] = __builtin_amdgcn_mfma_f32_16x16x32_bf16(vf, pb, zacc[ni], 0, 0, 0);
      }
    }

    __syncthreads();
    cur ^= 1;
  }

  // epilogue: store RAW partials (no /l, no /sqrt(D)); lane holds d=ni*16+g*4+r, q=qi
  const int bid = (h * 32 + blockIdx.x) * 2 + blockIdx.z;
  u16* zb = zp + (size_t)bid * 4096;
#pragma unroll
  for (int ni = 0; ni < 4; ++ni) {
    u32 a = packbf(zacc[ni][0], zacc[ni][1]);
    u32 b = packbf(zacc[ni][2], zacc[ni][3]);
    uint2 st = {a, b};
    *(uint2*)(zb + (size_t)(wv * 16 + qi) * 64 + ni * 16 + g * 4) = st;
  }
  if (g == 0) mlb[(size_t)bid * 64 + wv * 16 + qi] = make_float2(m, l);
}

// ---------------- split combine: zcat[q][h*64+d] = 0.125*(e0 z0 + e1 z1)/(e0 l0 + e1 l1) ----
__global__ __launch_bounds__(256) void comb_kernel(
    const u16* __restrict__ zp, const float2* __restrict__ mlb, u16* __restrict__ zcat)
{
  const int flat = blockIdx.x * 256 + threadIdx.x;   // 524288 total
  const int d4 = flat & 15;
  const int q = (flat >> 4) & 2047;
  const int h = flat >> 15;
  const int qt = q >> 6, qr = q & 63;
  const size_t pb = (size_t)(h * 32 + qt) * 2;
  const size_t base = pb * 4096 + (size_t)qr * 64 + d4 * 4;
  uint2 a = *(const uint2*)(zp + base);
  uint2 b = *(const uint2*)(zp + base + 4096);
  float2 ml0 = mlb[pb * 64 + qr];
  float2 ml1 = mlb[(pb + 1) * 64 + qr];
  const float M = fmaxf(ml0.x, ml1.x);
  const float e0 = __expf(ml0.x - M), e1 = __expf(ml1.x - M);
  const float s = 0.125f / (e0 * ml0.y + e1 * ml1.y);
  float o0 = (e0 * bf2f((u16)(a.x & 0xffff)) + e1 * bf2f((u16)(b.x & 0xffff))) * s;
  float o1 = (e0 * bf2f((u16)(a.x >> 16))   + e1 * bf2f((u16)(b.x >> 16))) * s;
  float o2 = (e0 * bf2f((u16)(a.y & 0xffff)) + e1 * bf2f((u16)(b.y & 0xffff))) * s;
  float o3 = (e0 * bf2f((u16)(a.y >> 16))   + e1 * bf2f((u16)(b.y >> 16))) * s;
  uint2 st;
  st.x = (u32)f2bf(o0) | ((u32)f2bf(o1) << 16);
  st.y = (u32)f2bf(o2) | ((u32)f2bf(o3) << 16);
  *(uint2*)(zcat + (size_t)q * EDIM + h * 64 + d4 * 4) = st;
}

// ---------------- LayerNorm over E=1024 ----------------
__global__ __launch_bounds__(256) void ln_kernel(
    const float* __restrict__ in, const float* __restrict__ g, const float* __restrict__ b,
    float* __restrict__ outf, u16* __restrict__ outb)
{
  const int row = blockIdx.x, t = threadIdx.x;
  const float4* rp = (const float4*)(in + (size_t)row * EDIM);
  float4 x = rp[t];
  float s = x.x + x.y + x.z + x.w;
  float sq = x.x * x.x + x.y * x.y + x.z * x.z + x.w * x.w;
#pragma unroll
  for (int m = 1; m < 64; m <<= 1) { s += __shfl_xor(s, m); sq += __shfl_xor(sq, m); }
  __shared__ float red[8];
  const int wv = t >> 6, lane = t & 63;
  if (lane == 0) { red[wv] = s; red[4 + wv] = sq; }
  __syncthreads();
  s = red[0] + red[1] + red[2] + red[3];
  sq = red[4] + red[5] + red[6] + red[7];
  const float mu = s * (1.f / EDIM);
  const float rs = rsqrtf(sq * (1.f / EDIM) - mu * mu + 1e-5f);
  float4 gg = ((const float4*)g)[t];
  float4 bb = ((const float4*)b)[t];
  float4 y;
  y.x = (x.x - mu) * rs * gg.x + bb.x;
  y.y = (x.y - mu) * rs * gg.y + bb.y;
  y.z = (x.z - mu) * rs * gg.z + bb.z;
  y.w = (x.w - mu) * rs * gg.w + bb.w;
  if (outf) ((float4*)(outf + (size_t)row * EDIM))[t] = y;
  if (outb) {
    uint2 pkv;
    pkv.x = (u32)f2bf(y.x) | ((u32)f2bf(y.y) << 16);
    pkv.y = (u32)f2bf(y.z) | ((u32)f2bf(y.w) << 16);
    ((uint2*)(outb + (size_t)row * EDIM))[t] = pkv;
  }
}

// ---------------- prep kernels ----------------
__global__ void emb_kernel(const float4* __restrict__ a, const float4* __restrict__ b,
                           float4* __restrict__ ef, uint2* __restrict__ eb)
{
  const int i = blockIdx.x * 256 + threadIdx.x;
  float4 x = a[i], y = b[i];
  float4 e; e.x = x.x + y.x; e.y = x.y + y.y; e.z = x.z + y.z; e.w = x.w + y.w;
  ef[i] = e;
  uint2 pk;
  pk.x = (u32)f2bf(e.x) | ((u32)f2bf(e.y) << 16);
  pk.y = (u32)f2bf(e.z) | ((u32)f2bf(e.w) << 16);
  eb[i] = pk;
}

__global__ void cvt_kernel(const float4* __restrict__ in, uint2* __restrict__ out, int n4)
{
  const int i = blockIdx.x * 256 + threadIdx.x;
  if (i >= n4) return;
  float4 x = in[i];
  uint2 pk;
  pk.x = (u32)f2bf(x.x) | ((u32)f2bf(x.y) << 16);
  pk.y = (u32)f2bf(x.z) | ((u32)f2bf(x.w) << 16);
  out[i] = pk;
}

__global__ void bias3_kernel(const float* __restrict__ bq, const float* __restrict__ bk,
                             const float* __restrict__ bv, float* __restrict__ o)
{
  const int i = blockIdx.x * 256 + threadIdx.x;
  if (i >= 3072) return;
  o[i] = i < 1024 ? bq[i] : (i < 2048 ? bk[i - 1024] : bv[i - 2048]);
}

// Wq/Wk/Wv [H,E,D] f32 -> Wqkvt [3*H*D, E] bf16 (row = (w*16+h)*64+d)
__global__ __launch_bounds__(256) void wqkv_kernel(
    const float* __restrict__ Wq, const float* __restrict__ Wk, const float* __restrict__ Wv,
    u16* __restrict__ outw)
{
  __shared__ float tile[64][65];
  const int et = blockIdx.x, h = blockIdx.y, wsel = blockIdx.z;
  const float* W = wsel == 0 ? Wq : (wsel == 1 ? Wk : Wv);
  const float* src = W + ((size_t)h * EDIM + et * 64) * DDIM;
  const int t = threadIdx.x;
#pragma unroll
  for (int it = 0; it < 4; ++it) {
    int fi = (t + it * 256) * 4;
    float4 v = *(const float4*)(src + fi);
    int e = fi >> 6, d = fi & 63;
    tile[e][d] = v.x; tile[e][d + 1] = v.y; tile[e][d + 2] = v.z; tile[e][d + 3] = v.w;
  }
  __syncthreads();
  const int d = t >> 2, ec = (t & 3) * 16;
  u16* dst = outw + ((size_t)(wsel * HNUM + h) * 64 + d) * EDIM + et * 64 + ec;
#pragma unroll
  for (int i = 0; i < 16; i += 2) {
    u32 p = (u32)f2bf(tile[ec + i][d]) | ((u32)f2bf(tile[ec + i + 1][d]) << 16);
    *(u32*)(dst + i) = p;
  }
}

// QKV [S,3072] v-part -> Vt [H,D,S] bf16
__global__ __launch_bounds__(256) void vt_kernel(const u16* __restrict__ qkv, u16* __restrict__ vt)
{
  __shared__ __align__(16) u16 tile[64][80];
  const int st = blockIdx.x, h = blockIdx.y, t = threadIdx.x;
  const int sr = t >> 2, dc = (t & 3) * 16;
  const u16* src = qkv + (size_t)(st * 64 + sr) * 3072 + 2048 + h * 64 + dc;
  *(uint4*)&tile[sr][dc] = *(const uint4*)src;
  *(uint4*)&tile[sr][dc + 8] = *(const uint4*)(src + 8);
  __syncthreads();
  const int d = t >> 2, sc = (t & 3) * 16;
  u16* dst = vt + ((size_t)h * 64 + d) * SLEN + st * 64 + sc;
#pragma unroll
  for (int i = 0; i < 16; i += 2) {
    u32 p = (u32)tile[sc + i][d] | ((u32)tile[sc + i + 1][d] << 16);
    *(u32*)(dst + i) = p;
  }
}

extern "C" void kernel_launch(void* const* d_in, const int* in_sizes, int n_in,
                              void* d_out, int out_size, void* d_ws, size_t ws_size,
                              hipStream_t stream) {
  const float* xw  = (const float*)d_in[0];
  const float* xp  = (const float*)d_in[1];
  const float* Wq  = (const float*)d_in[2];
  const float* bq  = (const float*)d_in[3];
  const float* Wk  = (const float*)d_in[4];
  const float* bk  = (const float*)d_in[5];
  const float* Wv  = (const float*)d_in[6];
  const float* bv  = (const float*)d_in[7];
  const float* W0  = (const float*)d_in[8];
  const float* b0  = (const float*)d_in[9];
  const float* g1  = (const float*)d_in[10];
  const float* be1 = (const float*)d_in[11];
  const float* W1  = (const float*)d_in[12];
  const float* b1  = (const float*)d_in[13];
  const float* W2  = (const float*)d_in[14];
  const float* b2  = (const float*)d_in[15];
  const float* g2  = (const float*)d_in[16];
  const float* be2 = (const float*)d_in[17];
  float* out = (float*)d_out;
  char* ws = (char*)d_ws;

  const size_t MB = 1ull << 20;
  // Lifetime-packed workspace, peak 64MB + 12KB. Stage order:
  // emb/cvt/wqkv -> QKVgemm -> vt -> attn -> comb -> W0gemm -> red2 -> LN1
  // -> W1gemm -> W2gemm -> red2 -> LN2
  float* embf32 = (float*)(ws + 0);          // emb -> red2(W0)          0..8
  u16*   embf16 = (u16*)(ws + 8 * MB);       // emb -> QKVgemm           8..12
  u16*   zcat   = (u16*)(ws + 8 * MB);       // comb -> W0gemm           8..12
  float* res2   = (float*)(ws + 8 * MB);     // red2(W2) -> LN2          8..16 (h1 head dead)
  u16*   Wqkvt  = (u16*)(ws + 12 * MB);      // wqkv -> QKVgemm          12..18
  u16*   h1     = (u16*)(ws + 12 * MB);      // W1gemm -> W2gemm         12..28
  u16*   QKV    = (u16*)(ws + 18 * MB);      // QKVgemm -> attn          18..30
  float* w0pA   = (float*)(ws + 18 * MB);    // W0gemm -> red2           18..26
  float* w0pB   = (float*)(ws + 26 * MB);    // W0gemm -> red2           26..34
  u16*   Vt     = (u16*)(ws + 30 * MB);      // vt -> attn               30..34
  u16*   zp     = (u16*)(ws + 34 * MB);      // attn -> comb             34..42
  float2* mlb   = (float2*)(ws + 42 * MB);   // attn -> comb             42..42.5
  float* res1   = (float*)(ws + 34 * MB);    // red2(W0) -> LN1          34..42 (zp dead)
  float* out1f  = (float*)(ws + 34 * MB);    // LN1 -> red2(W2)          34..42 (in-place)
  u16*   out1b  = (u16*)(ws + 28 * MB);      // LN1 -> W1gemm            28..32 (QKV tail+Vt dead; disjoint from h1)
  u16*   W0b    = (u16*)(ws + 46 * MB);      // cvt -> W0gemm            46..48
  u16*   W1b    = (u16*)(ws + 48 * MB);      // cvt -> W1gemm            48..56
  u16*   W2b    = (u16*)(ws + 56 * MB);      // cvt -> W2gemm            56..64
  float* w2pA   = (float*)(ws + 0);          // W2gemm -> red2           0..8  (embf32 dead)
  float* w2pB   = (float*)(ws + 48 * MB);    // W2gemm -> red2           48..56 (W1b dead)
  float* bias3  = (float*)(ws + 64 * MB);    // 12KB

  emb_kernel<<<2048, 256, 0, stream>>>((const float4*)xw, (const float4*)xp,
                                       (float4*)embf32, (uint2*)embf16);
  cvt_kernel<<<1024, 256, 0, stream>>>((const float4*)W0, (uint2*)W0b, 1024 * 1024 / 4);
  cvt_kernel<<<4096, 256, 0, stream>>>((const float4*)W1, (uint2*)W1b, 4096 * 1024 / 4);
  cvt_kernel<<<4096, 256, 0, stream>>>((const float4*)W2, (uint2*)W2b, 1024 * 4096 / 4);
  bias3_kernel<<<12, 256, 0, stream>>>(bq, bk, bv, bias3);
  wqkv_kernel<<<dim3(16, 16, 3), 256, 0, stream>>>(Wq, Wk, Wv, Wqkvt);

  // QKV projection (768 blocks = 3/CU)
  gemm_bt64<0><<<dim3(3072 / 128, 2048 / 64, 1), 256, 0, stream>>>(
      embf16, Wqkvt, bias3, nullptr, QKV, SLEN, 3072, 1024, 1024);

  vt_kernel<<<dim3(32, 16), 256, 0, stream>>>(QKV, Vt);

  // flash attention, KV-split-2 (1024 blocks = 4/CU)
  attn_kernel<<<dim3(SLEN / 64, HNUM, 2), 256, 0, stream>>>(QKV, Vt, zp, mlb);
  comb_kernel<<<2048, 256, 0, stream>>>(zp, mlb, zcat);

  // W0 proj, split-K=2 -> partials; red2 adds b0 + emb residual
  gemm_bt64<3><<<dim3(1024 / 128, 2048 / 64, 2), 256, 0, stream>>>(
      zcat, W0b, nullptr, w0pB, w0pA, SLEN, 1024, 1024, 512);
  red2_kernel<<<2048, 256, 0, stream>>>((const float4*)w0pA, (const float4*)w0pB,
                                        b0, (const float4*)embf32, (float4*)res1);

  ln_kernel<<<SLEN, 256, 0, stream>>>(res1, g1, be1, out1f, out1b);

  // FFN up + relu -> h1 (512 blocks = 2/CU)
  gemm_bt<1><<<dim3(4096 / 128, 2048 / 128), 256, 0, stream>>>(
      out1b, W1b, b1, nullptr, h1, SLEN, 4096, 1024);

  // FFN down, split-K=2 -> partials; red2 adds b2 + out1 residual
  gemm_bt64<3><<<dim3(1024 / 128, 2048 / 64, 2), 256, 0, stream>>>(
      h1, W2b, nullptr, w2pB, w2pA, SLEN, 1024, 4096, 2048);
  red2_kernel<<<2048, 256, 0, stream>>>((const float4*)w2pA, (const float4*)w2pB,
                                        b2, (const float4*)out1f, (float4*)res2);

  ln_kernel<<<SLEN, 256, 0, stream>>>(res2, g2, be2, out, nullptr);
}

// Round 7
// 169.324 us; speedup vs baseline: 1.4193x; 1.1056x over previous
//
#include <hip/hip_runtime.h>

#define SLEN 2048
#define EDIM 1024
#define HNUM 16
#define DDIM 64

typedef unsigned short u16;
typedef unsigned int u32;
typedef __attribute__((ext_vector_type(8))) __bf16 bf16x8;
typedef __attribute__((ext_vector_type(2))) __bf16 bf16x2;
typedef __attribute__((ext_vector_type(4))) float f32x4;
typedef __attribute__((ext_vector_type(16))) float f32x16;

__device__ __forceinline__ u16 f2bf(float f) {
  u32 u = __builtin_bit_cast(u32, f);
  u = (u + 0x7fffu + ((u >> 16) & 1u)) >> 16;
  return (u16)u;
}

__device__ __forceinline__ float bf2f(u16 v) {
  u32 u = ((u32)v) << 16;
  return __builtin_bit_cast(float, u);
}

__device__ __forceinline__ u32 packbf(float a, float b) {
  bf16x2 t; t[0] = (__bf16)a; t[1] = (__bf16)b;
  return __builtin_bit_cast(u32, t);
}

__device__ __forceinline__ void gload_lds16(const void* g, void* l) {
  __builtin_amdgcn_global_load_lds(
      (const __attribute__((address_space(1))) void*)g,
      (__attribute__((address_space(3))) void*)l, 16, 0, 0);
}

// XOR swizzle for 128B-row LDS tiles
__device__ __forceinline__ u32 swz(u32 b) { return b ^ (((b >> 7) & 7u) << 4); }

// ---------------- GEMM 128x128 tile: A [M,K] bf16, Bt [N,K] bf16 ----------------
template<int MODE>
__global__ __launch_bounds__(256, 2) void gemm_bt(
    const u16* __restrict__ A, const u16* __restrict__ Bt,
    const float* __restrict__ bias, const float* __restrict__ add,
    void* __restrict__ outp, int M, int N, int K)
{
  __shared__ __align__(16) u16 As[128 * 64];
  __shared__ __align__(16) u16 Bs[128 * 64];
  const int t = threadIdx.x;
  const int lane = t & 63, wv = t >> 6;
  const int bm = blockIdx.y * 128, bn = blockIdx.x * 128;
  const int wm = (wv >> 1) * 64, wn = (wv & 1) * 64;
  f32x4 acc[4][4] = {};

  const char* Ab = (const char*)A;
  const char* Bb = (const char*)Bt;

  for (int k0 = 0; k0 < K; k0 += 64) {
    __syncthreads();
#pragma unroll
    for (int j = 0; j < 4; ++j) {
      u32 bp = (u32)t * 16u + (u32)j * 4096u;
      u32 L = swz(bp);
      u32 row = L >> 7, colb = L & 127u;
      gload_lds16(Ab + ((size_t)(bm + row) * K + k0) * 2 + colb, (char*)As + bp);
      gload_lds16(Bb + ((size_t)(bn + row) * K + k0) * 2 + colb, (char*)Bs + bp);
    }
    __syncthreads();
#pragma unroll
    for (int ks = 0; ks < 2; ++ks) {
      bf16x8 af[4], bfr[4];
#pragma unroll
      for (int i = 0; i < 4; ++i) {
        u32 ra = (u32)(wm + i * 16 + (lane & 15));
        u32 La = (ra << 7) + (u32)ks * 64u + (u32)(lane >> 4) * 16u;
        af[i] = *(const bf16x8*)((const char*)As + (La ^ ((ra & 7u) << 4)));
        u32 rb = (u32)(wn + i * 16 + (lane & 15));
        u32 Lb = (rb << 7) + (u32)ks * 64u + (u32)(lane >> 4) * 16u;
        bfr[i] = *(const bf16x8*)((const char*)Bs + (Lb ^ ((rb & 7u) << 4)));
      }
#pragma unroll
      for (int mi = 0; mi < 4; ++mi)
#pragma unroll
        for (int ni = 0; ni < 4; ++ni)
          acc[mi][ni] = __builtin_amdgcn_mfma_f32_16x16x32_bf16(af[mi], bfr[ni], acc[mi][ni], 0, 0, 0);
    }
  }

  const int cr = (lane >> 4) * 4, cc = lane & 15;
#pragma unroll
  for (int ni = 0; ni < 4; ++ni) {
    const int col = bn + wn + ni * 16 + cc;
    const float bvv = bias[col];
#pragma unroll
    for (int mi = 0; mi < 4; ++mi) {
#pragma unroll
      for (int r = 0; r < 4; ++r) {
        const int row = bm + wm + mi * 16 + cr + r;
        float v = acc[mi][ni][r] + bvv;
        const size_t idx = (size_t)row * N + col;
        if constexpr (MODE == 0) ((u16*)outp)[idx] = f2bf(v);
        else if constexpr (MODE == 1) ((u16*)outp)[idx] = f2bf(v > 0.f ? v : 0.f);
        else ((float*)outp)[idx] = v + add[idx];
      }
    }
  }
}

// ---------------- GEMM 64x128 tile, optional split-K over blockIdx.z ----------------
// MODE 0: out bf16 = acc+bias ; MODE 3: f32 partial (no bias), z=0 -> outp, z=1 -> part1
template<int MODE>
__global__ __launch_bounds__(256, 4) void gemm_bt64(
    const u16* __restrict__ A, const u16* __restrict__ Bt,
    const float* __restrict__ bias, float* __restrict__ part1,
    void* __restrict__ outp, int M, int N, int lda, int KS)
{
  __shared__ __align__(16) u16 As[64 * 64];    // 8KB
  __shared__ __align__(16) u16 Bs[128 * 64];   // 16KB
  const int t = threadIdx.x;
  const int lane = t & 63, wv = t >> 6;
  const int bm = blockIdx.y * 64, bn = blockIdx.x * 128;
  const int wm = (wv >> 1) * 32, wn = (wv & 1) * 64;
  const int koff = blockIdx.z * KS;
  f32x4 acc[2][4] = {};

  const char* Ab = (const char*)A;
  const char* Bb = (const char*)Bt;

  for (int k0 = koff; k0 < koff + KS; k0 += 64) {
    __syncthreads();
    {
      u32 bp = (u32)t * 16u;
      u32 L = swz(bp);
      u32 row = L >> 7, colb = L & 127u;
      gload_lds16(Ab + ((size_t)(bm + row) * lda + k0) * 2 + colb, (char*)As + bp);
      u32 bp2 = bp + 4096u;
      u32 L2 = swz(bp2);
      u32 row2 = L2 >> 7, colb2 = L2 & 127u;
      gload_lds16(Ab + ((size_t)(bm + row2) * lda + k0) * 2 + colb2, (char*)As + bp2);
    }
#pragma unroll
    for (int j = 0; j < 4; ++j) {
      u32 bp = (u32)t * 16u + (u32)j * 4096u;
      u32 L = swz(bp);
      u32 row = L >> 7, colb = L & 127u;
      gload_lds16(Bb + ((size_t)(bn + row) * lda + k0) * 2 + colb, (char*)Bs + bp);
    }
    __syncthreads();
#pragma unroll
    for (int ks = 0; ks < 2; ++ks) {
      bf16x8 af[2], bfr[4];
#pragma unroll
      for (int i = 0; i < 2; ++i) {
        u32 ra = (u32)(wm + i * 16 + (lane & 15));
        u32 La = (ra << 7) + (u32)ks * 64u + (u32)(lane >> 4) * 16u;
        af[i] = *(const bf16x8*)((const char*)As + (La ^ ((ra & 7u) << 4)));
      }
#pragma unroll
      for (int i = 0; i < 4; ++i) {
        u32 rb = (u32)(wn + i * 16 + (lane & 15));
        u32 Lb = (rb << 7) + (u32)ks * 64u + (u32)(lane >> 4) * 16u;
        bfr[i] = *(const bf16x8*)((const char*)Bs + (Lb ^ ((rb & 7u) << 4)));
      }
#pragma unroll
      for (int mi = 0; mi < 2; ++mi)
#pragma unroll
        for (int ni = 0; ni < 4; ++ni)
          acc[mi][ni] = __builtin_amdgcn_mfma_f32_16x16x32_bf16(af[mi], bfr[ni], acc[mi][ni], 0, 0, 0);
    }
  }

  float* po = (MODE == 3 && blockIdx.z) ? part1 : (float*)outp;
  const int cr = (lane >> 4) * 4, cc = lane & 15;
#pragma unroll
  for (int ni = 0; ni < 4; ++ni) {
    const int col = bn + wn + ni * 16 + cc;
    const float bvv = (MODE == 3) ? 0.f : bias[col];
#pragma unroll
    for (int mi = 0; mi < 2; ++mi) {
#pragma unroll
      for (int r = 0; r < 4; ++r) {
        const int row = bm + wm + mi * 16 + cr + r;
        float v = acc[mi][ni][r] + bvv;
        const size_t idx = (size_t)row * N + col;
        if constexpr (MODE == 0) ((u16*)outp)[idx] = f2bf(v);
        else if constexpr (MODE == 1) ((u16*)outp)[idx] = f2bf(v > 0.f ? v : 0.f);
        else po[idx] = v;
      }
    }
  }
}

// ---------------- flash attention, 32x32 MFMA, KV-split-3 ----------------
// Block (qt, h, z): q-rows qt*128..+127 (4 waves x 32), keys: z<2 ? 768 : 512.
// Partials: zp bf16 [bid][128 q][64 d], mlb float2 [bid][128 q]; bid=(h*16+qt)*3+z.
__global__ __launch_bounds__(256, 4) void attn_kernel(
    const u16* __restrict__ qkv, const u16* __restrict__ vt,
    u16* __restrict__ zp, float2* __restrict__ mlb)
{
  __shared__ __align__(16) char lds[32768];  // 2 bufs x (K 8KB + Vt 8KB)
  const int t = threadIdx.x, lane = t & 63;
  const int q31 = lane & 31, hi = lane >> 5;
  const int wv = t >> 6;
  const int h = blockIdx.y;
  const int qrow = blockIdx.x * 128 + wv * 32 + q31;
  const int kt0 = blockIdx.z * 12;
  const int cnt = (blockIdx.z == 2) ? 8 : 12;

  // Q fragments (B-operand of swapped QK^T): lane holds Q[qrow][ds*16 + hi*8 + i]
  bf16x8 qf[4];
#pragma unroll
  for (int ds = 0; ds < 4; ++ds)
    qf[ds] = *(const bf16x8*)(qkv + (size_t)qrow * 3072 + h * 64 + ds * 16 + hi * 8);

  // staging (linear LDS dest, swizzled global src); K tile [64 kc][64 d], Vt tile [64 d][64 kc]
  const char* kgp[2];
  const char* vgp[2];
  u32 ldo[2];
#pragma unroll
  for (int j = 0; j < 2; ++j) {
    u32 bp = (u32)t * 16u + (u32)j * 4096u;
    u32 L = swz(bp);
    u32 row = L >> 7, colb = L & 127u;
    kgp[j] = (const char*)qkv + ((size_t)row * 3072 + 1024 + h * 64) * 2 + colb;
    vgp[j] = (const char*)vt + ((size_t)(h * 64 + row)) * (SLEN * 2) + colb;
    ldo[j] = bp;
  }

  f32x16 zacc[2] = {};   // zacc[dh][reg] = z^T[32*dh + (reg&3)+8*(reg>>2)+4*hi][q31]
  float m = -1e30f, l = 0.f;

  // prologue: stage tile kt0 into buf 0
  {
    size_t ko = (size_t)kt0 * (64 * 3072 * 2);
    int vo = kt0 * 128;
#pragma unroll
    for (int j = 0; j < 2; ++j) {
      gload_lds16(kgp[j] + ko, lds + ldo[j]);
      gload_lds16(vgp[j] + vo, lds + 8192 + ldo[j]);
    }
  }
  __syncthreads();

  int cur = 0;
  for (int it = 0; it < cnt; ++it) {
    const int kt = kt0 + it;
    if (it + 1 < cnt) {
      char* base = lds + (cur ^ 1) * 16384;
      size_t ko = (size_t)(kt + 1) * (64 * 3072 * 2);
      int vo = (kt + 1) * 128;
#pragma unroll
      for (int j = 0; j < 2; ++j) {
        gload_lds16(kgp[j] + ko, base + ldo[j]);
        gload_lds16(vgp[j] + vo, base + 8192 + ldo[j]);
      }
    }

    const char* Kl = lds + cur * 16384;
    const char* Vl = Kl + 8192;

#pragma unroll
    for (int kh = 0; kh < 2; ++kh) {
      // QK^T swapped: P[kc][q], kc = kh*32 + (reg&3)+8*(reg>>2)+4*hi, q = q31
      f32x16 p = {};
#pragma unroll
      for (int ds = 0; ds < 4; ++ds) {
        u32 rk = (u32)(kh * 32 + q31);
        u32 L = (rk << 7) + (u32)ds * 32u + (u32)hi * 16u;
        bf16x8 kf = *(const bf16x8*)(Kl + (L ^ ((rk & 7u) << 4)));
        p = __builtin_amdgcn_mfma_f32_32x32x16_bf16(kf, qf[ds], p, 0, 0, 0);
      }

      // online softmax (defer-max: rescale only when a new max appears)
      float tmax = p[0];
#pragma unroll
      for (int r = 1; r < 16; ++r) tmax = fmaxf(tmax, p[r]);
      tmax = fmaxf(tmax, __shfl_xor(tmax, 32));
      if (!__all(tmax <= m)) {
        float newm = fmaxf(m, tmax);
        float scl = __expf(m - newm);
        l *= scl;
#pragma unroll
        for (int r = 0; r < 16; ++r) { zacc[0][r] *= scl; zacc[1][r] *= scl; }
        m = newm;
      }
      float psum = 0.f;
      u32 w[8];
#pragma unroll
      for (int j = 0; j < 8; ++j) {
        float e0 = __expf(p[2 * j] - m);
        float e1 = __expf(p[2 * j + 1] - m);
        psum += e0 + e1;
        w[j] = packbf(e0, e1);
      }
      psum += __shfl_xor(psum, 32);
      l += psum;

      // PV: z^T[d][q] += V^T-frag(A) x P-frag(B).
      // B-frag words for kc-window ktl: word0/2 from swap(w[4ktl],w[4ktl+2]),
      // word1/3 from swap(w[4ktl+1],w[4ktl+3]) (permlane32_swap: a'=(a.lo,b.lo), b'=(a.hi,b.hi)).
#pragma unroll
      for (int ktl = 0; ktl < 2; ++ktl) {
        u32 A0 = w[4 * ktl + 0], B0 = w[4 * ktl + 2];
        asm volatile("v_permlane32_swap_b32 %0, %1" : "+v"(A0), "+v"(B0));
        u32 A1 = w[4 * ktl + 1], B1 = w[4 * ktl + 3];
        asm volatile("v_permlane32_swap_b32 %0, %1" : "+v"(A1), "+v"(B1));
        uint4 pw = {A0, A1, B0, B1};
        bf16x8 pf = __builtin_bit_cast(bf16x8, pw);
#pragma unroll
        for (int dh = 0; dh < 2; ++dh) {
          u32 rv = (u32)(dh * 32 + q31);
          u32 L = (rv << 7) + (u32)(kh * 64 + ktl * 32) + (u32)hi * 16u;
          bf16x8 vf = *(const bf16x8*)(Vl + (L ^ ((rv & 7u) << 4)));
          zacc[dh] = __builtin_amdgcn_mfma_f32_32x32x16_bf16(vf, pf, zacc[dh], 0, 0, 0);
        }
      }
    }
    __syncthreads();
    cur ^= 1;
  }

  // epilogue: raw partials; lane holds q=q31, d = dh*32 + 8g + 4hi + {0..3} (regs 4g..4g+3)
  const int bid = (h * 16 + blockIdx.x) * 3 + blockIdx.z;
  u16* zb = zp + (size_t)bid * 8192 + (size_t)(wv * 32 + q31) * 64;
#pragma unroll
  for (int dh = 0; dh < 2; ++dh)
#pragma unroll
    for (int g = 0; g < 4; ++g) {
      int d0 = dh * 32 + g * 8 + hi * 4;
      uint2 st;
      st.x = packbf(zacc[dh][4 * g + 0], zacc[dh][4 * g + 1]);
      st.y = packbf(zacc[dh][4 * g + 2], zacc[dh][4 * g + 3]);
      *(uint2*)(zb + d0) = st;
    }
  if (hi == 0) mlb[(size_t)bid * 128 + wv * 32 + q31] = make_float2(m, l);
}

// ---------------- split-3 combine: zcat[q][h*64+d] = 0.125 * sum(e_i z_i) / sum(e_i l_i) ----
__global__ __launch_bounds__(256) void comb_kernel(
    const u16* __restrict__ zp, const float2* __restrict__ mlb, u16* __restrict__ zcat)
{
  const int flat = blockIdx.x * 256 + threadIdx.x;   // 524288 total
  const int d4 = flat & 15;
  const int q = (flat >> 4) & 2047;
  const int h = flat >> 15;
  const int qt = q >> 7, qr = q & 127;
  const size_t pb = (size_t)(h * 16 + qt) * 3;
  const size_t base = pb * 8192 + (size_t)qr * 64 + d4 * 4;
  uint2 a = *(const uint2*)(zp + base);
  uint2 b = *(const uint2*)(zp + base + 8192);
  uint2 c = *(const uint2*)(zp + base + 16384);
  float2 ml0 = mlb[pb * 128 + qr];
  float2 ml1 = mlb[(pb + 1) * 128 + qr];
  float2 ml2 = mlb[(pb + 2) * 128 + qr];
  const float M = fmaxf(fmaxf(ml0.x, ml1.x), ml2.x);
  const float e0 = __expf(ml0.x - M), e1 = __expf(ml1.x - M), e2 = __expf(ml2.x - M);
  const float s = 0.125f / (e0 * ml0.y + e1 * ml1.y + e2 * ml2.y);
  float o0 = (e0 * bf2f((u16)(a.x & 0xffff)) + e1 * bf2f((u16)(b.x & 0xffff)) + e2 * bf2f((u16)(c.x & 0xffff))) * s;
  float o1 = (e0 * bf2f((u16)(a.x >> 16))   + e1 * bf2f((u16)(b.x >> 16))   + e2 * bf2f((u16)(c.x >> 16))) * s;
  float o2 = (e0 * bf2f((u16)(a.y & 0xffff)) + e1 * bf2f((u16)(b.y & 0xffff)) + e2 * bf2f((u16)(c.y & 0xffff))) * s;
  float o3 = (e0 * bf2f((u16)(a.y >> 16))   + e1 * bf2f((u16)(b.y >> 16))   + e2 * bf2f((u16)(c.y >> 16))) * s;
  uint2 st;
  st.x = (u32)f2bf(o0) | ((u32)f2bf(o1) << 16);
  st.y = (u32)f2bf(o2) | ((u32)f2bf(o3) << 16);
  *(uint2*)(zcat + (size_t)q * EDIM + h * 64 + d4 * 4) = st;
}

// ---------------- fused split-K reduce + LayerNorm: x = pA+pB+bias+add; LN(x) ----------------
__global__ __launch_bounds__(256) void lnred_kernel(
    const float4* __restrict__ pA, const float4* __restrict__ pB,
    const float* __restrict__ bias, const float4* __restrict__ add,
    const float* __restrict__ g, const float* __restrict__ b,
    float* __restrict__ outf, u16* __restrict__ outb)
{
  const int row = blockIdx.x, t = threadIdx.x;
  const int i = row * 256 + t;
  float4 a = pA[i], p2 = pB[i], c = add[i];
  float4 bs = ((const float4*)bias)[t];
  float4 x;
  x.x = a.x + p2.x + c.x + bs.x;
  x.y = a.y + p2.y + c.y + bs.y;
  x.z = a.z + p2.z + c.z + bs.z;
  x.w = a.w + p2.w + c.w + bs.w;
  float s = x.x + x.y + x.z + x.w;
  float sq = x.x * x.x + x.y * x.y + x.z * x.z + x.w * x.w;
#pragma unroll
  for (int msk = 1; msk < 64; msk <<= 1) { s += __shfl_xor(s, msk); sq += __shfl_xor(sq, msk); }
  __shared__ float red[8];
  const int wv = t >> 6, lane = t & 63;
  if (lane == 0) { red[wv] = s; red[4 + wv] = sq; }
  __syncthreads();
  s = red[0] + red[1] + red[2] + red[3];
  sq = red[4] + red[5] + red[6] + red[7];
  const float mu = s * (1.f / EDIM);
  const float rs = rsqrtf(sq * (1.f / EDIM) - mu * mu + 1e-5f);
  float4 gg = ((const float4*)g)[t];
  float4 bb = ((const float4*)b)[t];
  float4 y;
  y.x = (x.x - mu) * rs * gg.x + bb.x;
  y.y = (x.y - mu) * rs * gg.y + bb.y;
  y.z = (x.z - mu) * rs * gg.z + bb.z;
  y.w = (x.w - mu) * rs * gg.w + bb.w;
  if (outf) ((float4*)(outf + (size_t)row * EDIM))[t] = y;
  if (outb) {
    uint2 pkv;
    pkv.x = (u32)f2bf(y.x) | ((u32)f2bf(y.y) << 16);
    pkv.y = (u32)f2bf(y.z) | ((u32)f2bf(y.w) << 16);
    ((uint2*)(outb + (size_t)row * EDIM))[t] = pkv;
  }
}

// ---------------- prep kernels ----------------
__global__ void emb_kernel(const float4* __restrict__ a, const float4* __restrict__ b,
                           float4* __restrict__ ef, uint2* __restrict__ eb)
{
  const int i = blockIdx.x * 256 + threadIdx.x;
  float4 x = a[i], y = b[i];
  float4 e; e.x = x.x + y.x; e.y = x.y + y.y; e.z = x.z + y.z; e.w = x.w + y.w;
  ef[i] = e;
  uint2 pk;
  pk.x = (u32)f2bf(e.x) | ((u32)f2bf(e.y) << 16);
  pk.y = (u32)f2bf(e.z) | ((u32)f2bf(e.w) << 16);
  eb[i] = pk;
}

__global__ void cvt_kernel(const float4* __restrict__ in, uint2* __restrict__ out, int n4)
{
  const int i = blockIdx.x * 256 + threadIdx.x;
  if (i >= n4) return;
  float4 x = in[i];
  uint2 pk;
  pk.x = (u32)f2bf(x.x) | ((u32)f2bf(x.y) << 16);
  pk.y = (u32)f2bf(x.z) | ((u32)f2bf(x.w) << 16);
  out[i] = pk;
}

__global__ void bias3_kernel(const float* __restrict__ bq, const float* __restrict__ bk,
                             const float* __restrict__ bv, float* __restrict__ o)
{
  const int i = blockIdx.x * 256 + threadIdx.x;
  if (i >= 3072) return;
  o[i] = i < 1024 ? bq[i] : (i < 2048 ? bk[i - 1024] : bv[i - 2048]);
}

// Wq/Wk/Wv [H,E,D] f32 -> Wqkvt [3*H*D, E] bf16 (row = (w*16+h)*64+d)
__global__ __launch_bounds__(256) void wqkv_kernel(
    const float* __restrict__ Wq, const float* __restrict__ Wk, const float* __restrict__ Wv,
    u16* __restrict__ outw)
{
  __shared__ float tile[64][65];
  const int et = blockIdx.x, h = blockIdx.y, wsel = blockIdx.z;
  const float* W = wsel == 0 ? Wq : (wsel == 1 ? Wk : Wv);
  const float* src = W + ((size_t)h * EDIM + et * 64) * DDIM;
  const int t = threadIdx.x;
#pragma unroll
  for (int it = 0; it < 4; ++it) {
    int fi = (t + it * 256) * 4;
    float4 v = *(const float4*)(src + fi);
    int e = fi >> 6, d = fi & 63;
    tile[e][d] = v.x; tile[e][d + 1] = v.y; tile[e][d + 2] = v.z; tile[e][d + 3] = v.w;
  }
  __syncthreads();
  const int d = t >> 2, ec = (t & 3) * 16;
  u16* dst = outw + ((size_t)(wsel * HNUM + h) * 64 + d) * EDIM + et * 64 + ec;
#pragma unroll
  for (int i = 0; i < 16; i += 2) {
    u32 p = (u32)f2bf(tile[ec + i][d]) | ((u32)f2bf(tile[ec + i + 1][d]) << 16);
    *(u32*)(dst + i) = p;
  }
}

// QKV [S,3072] v-part -> Vt [H,D,S] bf16
__global__ __launch_bounds__(256) void vt_kernel(const u16* __restrict__ qkv, u16* __restrict__ vt)
{
  __shared__ __align__(16) u16 tile[64][80];
  const int st = blockIdx.x, h = blockIdx.y, t = threadIdx.x;
  const int sr = t >> 2, dc = (t & 3) * 16;
  const u16* src = qkv + (size_t)(st * 64 + sr) * 3072 + 2048 + h * 64 + dc;
  *(uint4*)&tile[sr][dc] = *(const uint4*)src;
  *(uint4*)&tile[sr][dc + 8] = *(const uint4*)(src + 8);
  __syncthreads();
  const int d = t >> 2, sc = (t & 3) * 16;
  u16* dst = vt + ((size_t)h * 64 + d) * SLEN + st * 64 + sc;
#pragma unroll
  for (int i = 0; i < 16; i += 2) {
    u32 p = (u32)tile[sc + i][d] | ((u32)tile[sc + i + 1][d] << 16);
    *(u32*)(dst + i) = p;
  }
}

extern "C" void kernel_launch(void* const* d_in, const int* in_sizes, int n_in,
                              void* d_out, int out_size, void* d_ws, size_t ws_size,
                              hipStream_t stream) {
  const float* xw  = (const float*)d_in[0];
  const float* xp  = (const float*)d_in[1];
  const float* Wq  = (const float*)d_in[2];
  const float* bq  = (const float*)d_in[3];
  const float* Wk  = (const float*)d_in[4];
  const float* bk  = (const float*)d_in[5];
  const float* Wv  = (const float*)d_in[6];
  const float* bv  = (const float*)d_in[7];
  const float* W0  = (const float*)d_in[8];
  const float* b0  = (const float*)d_in[9];
  const float* g1  = (const float*)d_in[10];
  const float* be1 = (const float*)d_in[11];
  const float* W1  = (const float*)d_in[12];
  const float* b1  = (const float*)d_in[13];
  const float* W2  = (const float*)d_in[14];
  const float* b2  = (const float*)d_in[15];
  const float* g2  = (const float*)d_in[16];
  const float* be2 = (const float*)d_in[17];
  float* out = (float*)d_out;
  char* ws = (char*)d_ws;

  const size_t MB = 1ull << 20;
  // Lifetime-packed workspace (audited pairwise per kernel), peak 64MB + 12KB:
  float* embf32 = (float*)(ws + 0);          // emb -> lnred1            0..8
  u16*   embf16 = (u16*)(ws + 8 * MB);       // emb -> QKVgemm           8..12
  u16*   zcat   = (u16*)(ws + 8 * MB);       // comb -> W0gemm           8..12 (embf16 dead)
  u16*   out1b  = (u16*)(ws + 8 * MB);       // lnred1 -> W1gemm         8..12 (zcat dead)
  u16*   Wqkvt  = (u16*)(ws + 12 * MB);      // wqkv -> QKVgemm          12..18
  float2* mlb   = (float2*)(ws + 12 * MB);   // attn -> comb             12..12.75 (Wqkvt dead)
  u16*   h1     = (u16*)(ws + 12 * MB);      // W1gemm -> W2gemm         12..28
  u16*   QKV    = (u16*)(ws + 18 * MB);      // QKVgemm -> attn          18..30
  float* w0pA   = (float*)(ws + 18 * MB);    // W0gemm -> lnred1         18..26 (QKV dead)
  float* w0pB   = (float*)(ws + 26 * MB);    // W0gemm -> lnred1         26..34
  u16*   Vt     = (u16*)(ws + 30 * MB);      // vt -> attn               30..34
  u16*   zp     = (u16*)(ws + 34 * MB);      // attn -> comb             34..46 (12MB)
  float* out1f  = (float*)(ws + 34 * MB);    // lnred1 -> lnred2         34..42 (zp dead)
  u16*   W0b    = (u16*)(ws + 46 * MB);      // cvt -> W0gemm            46..48
  u16*   W1b    = (u16*)(ws + 48 * MB);      // cvt -> W1gemm            48..56
  u16*   W2b    = (u16*)(ws + 56 * MB);      // cvt -> W2gemm            56..64
  float* w2pA   = (float*)(ws + 0);          // W2gemm -> lnred2         0..8  (embf32 dead)
  float* w2pB   = (float*)(ws + 42 * MB);    // W2gemm -> lnred2         42..50 (zp/W0b/W1b-head dead)
  float* bias3  = (float*)(ws + 64 * MB);    // 12KB

  emb_kernel<<<2048, 256, 0, stream>>>((const float4*)xw, (const float4*)xp,
                                       (float4*)embf32, (uint2*)embf16);
  cvt_kernel<<<1024, 256, 0, stream>>>((const float4*)W0, (uint2*)W0b, 1024 * 1024 / 4);
  cvt_kernel<<<4096, 256, 0, stream>>>((const float4*)W1, (uint2*)W1b, 4096 * 1024 / 4);
  cvt_kernel<<<4096, 256, 0, stream>>>((const float4*)W2, (uint2*)W2b, 1024 * 4096 / 4);
  bias3_kernel<<<12, 256, 0, stream>>>(bq, bk, bv, bias3);
  wqkv_kernel<<<dim3(16, 16, 3), 256, 0, stream>>>(Wq, Wk, Wv, Wqkvt);

  // QKV projection (768 blocks = 3/CU)
  gemm_bt64<0><<<dim3(3072 / 128, 2048 / 64, 1), 256, 0, stream>>>(
      embf16, Wqkvt, bias3, nullptr, QKV, SLEN, 3072, 1024, 1024);

  vt_kernel<<<dim3(32, 16), 256, 0, stream>>>(QKV, Vt);

  // flash attention 32x32, KV-split-3 (768 blocks = 3/CU)
  attn_kernel<<<dim3(SLEN / 128, HNUM, 3), 256, 0, stream>>>(QKV, Vt, zp, mlb);
  comb_kernel<<<2048, 256, 0, stream>>>(zp, mlb, zcat);

  // W0 proj, split-K=2 -> partials; lnred1 adds b0 + emb residual and does LN1
  gemm_bt64<3><<<dim3(1024 / 128, 2048 / 64, 2), 256, 0, stream>>>(
      zcat, W0b, nullptr, w0pB, w0pA, SLEN, 1024, 1024, 512);
  lnred_kernel<<<SLEN, 256, 0, stream>>>((const float4*)w0pA, (const float4*)w0pB,
                                         b0, (const float4*)embf32, g1, be1, out1f, out1b);

  // FFN up + relu -> h1 (512 blocks = 2/CU)
  gemm_bt<1><<<dim3(4096 / 128, 2048 / 128), 256, 0, stream>>>(
      out1b, W1b, b1, nullptr, h1, SLEN, 4096, 1024);

  // FFN down, split-K=2 -> partials; lnred2 adds b2 + out1 residual and does LN2 -> out
  gemm_bt64<3><<<dim3(1024 / 128, 2048 / 64, 2), 256, 0, stream>>>(
      h1, W2b, nullptr, w2pB, w2pA, SLEN, 1024, 4096, 2048);
  lnred_kernel<<<SLEN, 256, 0, stream>>>((const float4*)w2pA, (const float4*)w2pB,
                                         b2, (const float4*)out1f, g2, be2, out, nullptr);
}